// Round 6
// baseline (2776.394 us; speedup 1.0000x reference)
//
#include <hip/hip_runtime.h>
#include <cstdint>

typedef _Float16 f16;
typedef _Float16 f16x8 __attribute__((ext_vector_type(8)));
typedef float f32x4 __attribute__((ext_vector_type(4)));
typedef unsigned int u32;

#define DEV __device__ __forceinline__

DEV void gll16(const void* g, void* l) {
  __builtin_amdgcn_global_load_lds((const __attribute__((address_space(1))) u32*)g,
                                   (__attribute__((address_space(3))) u32*)l, 16, 0, 0);
}

// ---- LLC-coherent (cross-XCD) access helpers: sc0 sc1 bypass per-XCD L2 ----
DEV f32x4 ld16c(const void* p) {
  f32x4 r;
  asm volatile("global_load_dwordx4 %0, %1, off sc0 sc1" : "=&v"(r) : "v"(p) : "memory");
  return r;
}
DEV void vmwait() {
  asm volatile("s_waitcnt vmcnt(0)" ::: "memory");
  __builtin_amdgcn_sched_barrier(0);
}
DEV void st16c(void* p, f32x4 v) {
  asm volatile("global_store_dwordx4 %0, %1, off sc0 sc1" :: "v"(p), "v"(v) : "memory");
}
DEV void st4c(void* p, float v) {
  asm volatile("global_store_dword %0, %1, off sc0 sc1" :: "v"(p), "v"(v) : "memory");
}
DEV void st2c(void* p, f16 v) {
  unsigned short w; __builtin_memcpy(&w, &v, 2);
  u32 ww = w;
  asm volatile("global_store_short %0, %1, off sc0 sc1" :: "v"(p), "v"(ww) : "memory");
}
DEV f16x8 asf16(f32x4 v) { f16x8 r; __builtin_memcpy(&r, &v, 16); return r; }
DEV f32x4 asf32(f16x8 v) { f32x4 r; __builtin_memcpy(&r, &v, 16); return r; }

DEV float wsum(float v) {
#pragma unroll
  for (int o = 32; o; o >>= 1) v += __shfl_xor(v, o);
  return v;
}

struct MP {
  const int* tok; const float* etab;
  const float* Wq; const float* bq; const float* Wk; const float* bk;
  const float* Wv; const float* bv; const float* Wo; const float* bo;
  const float* ln1g; const float* ln1b; const float* ln2g; const float* ln2b;
  const float* Wfc; const float* bfc; const float* Wpr; const float* bpr;
  const float* rw1; const float* rw2; const float* Wfin; const float* bfin;
  const float* lnfg; const float* lnfb;
  f16* actA; float* rawA; float* rawB; float* rawC; float* rawD; float* ssq;
  f16* qhat; f16* khat; f16* vT; f16* ao; f16* fcact;
  f16* wqkvT; f16* woT; f16* wfcT; f16* wprT; f16* wfinT;
  u32* bar; float* out;
};

DEV u32 ld_rlx(u32* p) { return __hip_atomic_load(p, __ATOMIC_RELAXED, __HIP_MEMORY_SCOPE_AGENT); }
DEV u32 inc_rlx(u32* p) { return __hip_atomic_fetch_add(p, 1u, __ATOMIC_RELAXED, __HIP_MEMORY_SCOPE_AGENT); }

// ---- one-time init barrier: flat 256, full fences ----
DEV void gbar_init(u32* bar) {
  __syncthreads();
  if (threadIdx.x == 0) {
    u32* root0 = bar + 352;
    u32* gen0 = bar + 384;
    u32 g = ld_rlx(gen0);
    __builtin_amdgcn_fence(__ATOMIC_RELEASE, "agent");
    u32 a = inc_rlx(root0);
    if ((a & 255u) == 255u) {
      __hip_atomic_store(gen0, g + 1u, __ATOMIC_RELEASE, __HIP_MEMORY_SCOPE_AGENT);
    } else {
      for (int it = 0; it < (1 << 22); ++it) {
        if (ld_rlx(gen0) != g) break;
        __builtin_amdgcn_s_sleep(2);
      }
    }
    __builtin_amdgcn_fence(__ATOMIC_ACQUIRE, "agent");
  }
  __syncthreads();
}

// ---- heavy barrier (L2 writeback+inv): used ONCE after weight transpose ----
DEV void gbar_heavy(u32* bar, u32 myxcc, u32 Nx, u32 NXCD) {
  __syncthreads();
  if (threadIdx.x == 0) {
    u32* cnt = bar + 64 + myxcc * 32;
    u32* root = bar + 0;
    u32* gen = bar + 32;
    u32 g = ld_rlx(gen);
    asm volatile("s_waitcnt vmcnt(0) lgkmcnt(0)" ::: "memory");
    u32 a = inc_rlx(cnt);
    bool flipped = false;
    if (a % Nx == Nx - 1u) {
      __builtin_amdgcn_fence(__ATOMIC_RELEASE, "agent");
      asm volatile("s_waitcnt vmcnt(0)" ::: "memory");
      u32 b = inc_rlx(root);
      if (b % NXCD == NXCD - 1u) {
        __hip_atomic_store(gen, g + 1u, __ATOMIC_RELEASE, __HIP_MEMORY_SCOPE_AGENT);
        flipped = true;
      }
    }
    if (!flipped) {
      for (int it = 0; it < (1 << 22); ++it) {
        if (ld_rlx(gen) != g) break;
        __builtin_amdgcn_s_sleep(2);
      }
    }
    __builtin_amdgcn_fence(__ATOMIC_ACQUIRE, "agent");
  }
  __syncthreads();
}

// ---- light barrier: NO cache fences. Cross-phase data is sc0sc1-coherent. ----
DEV void gbar_light(u32* bar, u32 myxcc, u32 Nx, u32 NXCD) {
  __syncthreads();  // drains each wave's vmcnt (compiler emits waitcnt before s_barrier)
  if (threadIdx.x == 0) {
    u32* cnt = bar + 64 + myxcc * 32;
    u32* root = bar + 0;
    u32* gen = bar + 32;
    u32 g = ld_rlx(gen);
    u32 a = inc_rlx(cnt);
    bool flipped = false;
    if (a % Nx == Nx - 1u) {
      u32 b = inc_rlx(root);
      if (b % NXCD == NXCD - 1u) {
        __hip_atomic_store(gen, g + 1u, __ATOMIC_RELAXED, __HIP_MEMORY_SCOPE_AGENT);
        flipped = true;
      }
    }
    if (!flipped) {
      for (int it = 0; it < (1 << 22); ++it) {
        if (ld_rlx(gen) != g) break;
        __builtin_amdgcn_s_sleep(2);
      }
    }
    __builtin_amdgcn_sched_barrier(0);
  }
  __syncthreads();
}

// ---- 64x64 f32->f16 transpose tile through LDS (phase 0 only, cached) ----
DEV void trans_tile(const float* W, f16* BT, int K, int N, int ldk, int n0, int k0,
                    char* SM) {
  float* tile = (float*)SM;  // [64][65]
  const int tid = threadIdx.x;
  const int c = tid & 63, r0 = tid >> 6;
#pragma unroll
  for (int i = 0; i < 8; i++) {
    int kr = r0 + i * 8;
    int k = k0 + kr, n = n0 + c;
    tile[kr * 65 + c] = (k < K && n < N) ? W[(size_t)k * N + n] : 0.f;
  }
  __syncthreads();
#pragma unroll
  for (int i = 0; i < 8; i++) {
    int nn = r0 + i * 8;
    BT[(size_t)(n0 + nn) * ldk + k0 + c] = (f16)tile[c * 65 + nn];
  }
  __syncthreads();
}

// ---- 128x128 GEMM task: A direct-to-reg (LLC-coherent), B via gll16 (L2-cached) ----
template <int EPI>
DEV void gemm_task(const f16* A, const f16* B, int lda, int ldb, int tm, int tn,
                   int kbeg, int ksteps, float* O, const float* c0, const float* c1,
                   const float* c2, float* ssq, f16* H1, f16* H2, f16* H3,
                   int addR1, char* SM) {
  const int tid = threadIdx.x, wid = tid >> 6, lane = tid & 63;
  const int l15 = lane & 15, l4 = lane >> 4;
  const int wm = wid & 3, wn = wid >> 2;
  const int m0 = tm * 128, n0 = tn * 128;
  f32x4 acc[2][4];
#pragma unroll
  for (int i = 0; i < 2; i++)
#pragma unroll
    for (int j = 0; j < 4; j++) acc[i][j] = (f32x4){0.f, 0.f, 0.f, 0.f};
  const size_t ldab = (size_t)lda * 2, ldbb = (size_t)ldb * 2;
  // A fragment addresses: row = m0+wm*32+i*16+l15, k-byte = kbeg*2 + ks*128 + kk*64 + l4*16
  const char* Arow0 = (const char*)A + (size_t)(m0 + wm * 32 + l15) * ldab +
                      (size_t)kbeg * 2 + (size_t)l4 * 16;
  const size_t Ai = (size_t)16 * ldab;
  const int swz = ((lane & 7) ^ (lane >> 3)) * 16;
  const char* Bb = (const char*)B + (size_t)(n0 + (lane >> 3)) * ldbb + swz + (size_t)kbeg * 2;
  auto stageB = [&](int buf, int ks) {  // 2 gll16 per wave
    char* db = SM + buf * 16384;
    for (int i = wid; i < 16; i += 8) gll16(Bb + (size_t)(i * 8) * ldbb + ks * 128, db + i * 1024);
  };
  f32x4 a_cur[4], a_nxt[4];
  a_cur[0] = ld16c(Arow0);           a_cur[1] = ld16c(Arow0 + 64);
  a_cur[2] = ld16c(Arow0 + Ai);      a_cur[3] = ld16c(Arow0 + Ai + 64);
  stageB(0, 0);
  vmwait();
  __builtin_amdgcn_s_barrier();
  int cur = 0;
  for (int ks = 0; ks < ksteps; ks++) {
    if (ks + 1 < ksteps) {
      const char* Ab2 = Arow0 + (size_t)(ks + 1) * 128;
      a_nxt[0] = ld16c(Ab2);          a_nxt[1] = ld16c(Ab2 + 64);
      a_nxt[2] = ld16c(Ab2 + Ai);     a_nxt[3] = ld16c(Ab2 + Ai + 64);
      stageB(cur ^ 1, ks + 1);
    }
    const f16* sB = (const f16*)(SM + cur * 16384);
#pragma unroll
    for (int kk = 0; kk < 2; kk++) {
      f16x8 bf[4];
#pragma unroll
      for (int j = 0; j < 4; j++) {
        int row = wn * 64 + j * 16 + l15;
        bf[j] = *(const f16x8*)(sB + row * 64 + (((kk * 4 + l4) ^ (l15 & 7)) * 8));
      }
#pragma unroll
      for (int i = 0; i < 2; i++) {
        f16x8 af = asf16(a_cur[i * 2 + kk]);
#pragma unroll
        for (int j = 0; j < 4; j++)
          acc[i][j] = __builtin_amdgcn_mfma_f32_16x16x32_f16(af, bf[j], acc[i][j], 0, 0, 0);
      }
    }
    vmwait();
    __builtin_amdgcn_s_barrier();
    if (ks + 1 < ksteps) {
#pragma unroll
      for (int q = 0; q < 4; q++) a_cur[q] = a_nxt[q];
    }
    cur ^= 1;
  }
  if (EPI == 0) {
#pragma unroll
    for (int i = 0; i < 2; i++) {
      int row = m0 + wm * 32 + i * 16 + l4 * 4;
#pragma unroll
      for (int j = 0; j < 4; j++) {
        int col = n0 + wn * 64 + j * 16 + l15;
#pragma unroll
        for (int r = 0; r < 4; r++) st4c(&O[(size_t)(row + r) * 520 + col + 1], acc[i][j][r]);
      }
    }
  } else if (EPI == 1) {
    const int cb = (n0 >> 6) + wn;
    const int typ = cb >> 3, h = cb & 7;
    const float* bb = (typ == 0) ? c0 : (typ == 1) ? c1 : c2;
    float bj[4];
#pragma unroll
    for (int j = 0; j < 4; j++) bj[j] = bb[h * 64 + j * 16 + l15];
    const float qs = (typ == 0) ? 0.25f : 1.0f;
#pragma unroll
    for (int i = 0; i < 2; i++) {
#pragma unroll
      for (int r = 0; r < 4; r++) {
        float y[4], ss = 0.f;
#pragma unroll
        for (int j = 0; j < 4; j++) { y[j] = acc[i][j][r] + bj[j]; ss += y[j] * y[j]; }
        ss += __shfl_xor(ss, 1); ss += __shfl_xor(ss, 2);
        ss += __shfl_xor(ss, 4); ss += __shfl_xor(ss, 8);
        float t = sqrtf(ss + 1.f);
        int row = m0 + wm * 32 + i * 16 + l4 * 4 + r;
        int b = row >> 10, s = row & 1023, bh = b * 8 + h;
        if (typ < 2) {
          f16* dst = typ ? H2 : H1;
          size_t base = ((size_t)bh * 1024 + s) * 88;
#pragma unroll
          for (int j = 0; j < 4; j++) st2c(&dst[base + j * 16 + l15], (f16)(qs * y[j]));
          if (l15 == 0) st2c(&dst[base + 64], (f16)(qs * t));
        } else {
#pragma unroll
          for (int j = 0; j < 4; j++)
            st2c(&H3[((size_t)bh * 80 + j * 16 + l15) * 1024 + s], (f16)y[j]);
          if (l15 == 0) st2c(&H3[((size_t)bh * 80 + 64) * 1024 + s], (f16)t);
        }
      }
    }
  } else if (EPI == 2) {
#pragma unroll
    for (int i = 0; i < 2; i++) {
#pragma unroll
      for (int r = 0; r < 4; r++) {
        int row = m0 + wm * 32 + i * 16 + l4 * 4 + r;
        float ss = 0.f;
#pragma unroll
        for (int j = 0; j < 4; j++) {
          int col = n0 + wn * 64 + j * 16 + l15;
          float gg = 0.f;
          if (col < 2047) {
            float yv = acc[i][j][r] + c0[col];
            float z = 0.7978845608f * (yv + 0.044715f * yv * yv * yv);
            float th = 1.f - 2.f / (__expf(2.f * z) + 1.f);
            gg = 0.5f * yv * (1.f + th);
          }
          ss += gg * gg;
          st2c(&H1[(size_t)row * 2048 + col], (f16)gg);
        }
        ss += __shfl_xor(ss, 1); ss += __shfl_xor(ss, 2);
        ss += __shfl_xor(ss, 4); ss += __shfl_xor(ss, 8);
        if (l15 == 0) atomicAdd(ssq + row, ss);
      }
    }
  } else {
#pragma unroll
    for (int i = 0; i < 2; i++) {
#pragma unroll
      for (int r = 0; r < 4; r++) {
        int row = m0 + wm * 32 + i * 16 + l4 * 4 + r;
        float t = 0.f;
        if (addR1) t = sqrtf(__hip_atomic_load(&ssq[row], __ATOMIC_RELAXED,
                                               __HIP_MEMORY_SCOPE_AGENT) + 1.f);
#pragma unroll
        for (int j = 0; j < 4; j++) {
          int col = n0 + wn * 64 + j * 16 + l15;
          float v = acc[i][j][r];
          if (addR1) v += t * ((col < 511) ? c0[col] : 0.f);
          st4c(&O[(size_t)row * 520 + col + 1], v);
        }
      }
    }
  }
}

// ---- per-wave flash attention + l_project (Q/K/V cached: versioned buffers) ----
DEV void attn_task(int t, const f16* qhat, const f16* khat, const f16* vT, f16* ao,
                   char* sPb) {
  const int lane = threadIdx.x & 63;
  const int bh = t & 15, rt = 63 - (t >> 4);
  const int l15 = lane & 15, l4 = lane >> 4;
  f16* sP = (f16*)sPb;
  const f16* qp = qhat + ((size_t)bh * 1024 + rt * 16) * 88;
  const f16* kp = khat + (size_t)bh * 1024 * 88;
  const f16* vp = vT + (size_t)bh * 80 * 1024;
  f16x8 qf0 = *(const f16x8*)(qp + l15 * 88 + l4 * 8);
  f16x8 qf1 = *(const f16x8*)(qp + l15 * 88 + 32 + l4 * 8);
  float qth[4];
#pragma unroll
  for (int r = 0; r < 4; r++) qth[r] = (float)qp[(l4 * 4 + r) * 88 + 64];
  f32x4 acc[5];
#pragma unroll
  for (int i = 0; i < 5; i++) acc[i] = (f32x4){0, 0, 0, 0};
  float mrun[4] = {-3e38f, -3e38f, -3e38f, -3e38f}, lrun[4] = {0, 0, 0, 0};
  const int nt = (rt >> 2) + 1;
  for (int jt = 0; jt < nt; ++jt) {
    const int j0 = jt * 64;
    const bool dt = (jt == nt - 1);
    f32x4 sc[4];
#pragma unroll
    for (int fn = 0; fn < 4; fn++) {
      const f16* kb = kp + (size_t)(j0 + fn * 16 + l15) * 88;
      f16x8 k0v = *(const f16x8*)(kb + l4 * 8);
      f16x8 k1v = *(const f16x8*)(kb + 32 + l4 * 8);
      f32x4 a = (f32x4){0, 0, 0, 0};
      a = __builtin_amdgcn_mfma_f32_16x16x32_f16(qf0, k0v, a, 0, 0, 0);
      a = __builtin_amdgcn_mfma_f32_16x16x32_f16(qf1, k1v, a, 0, 0, 0);
      sc[fn] = a;
    }
    float s[4][4];
#pragma unroll
    for (int fn = 0; fn < 4; fn++) {
      float ktc = (float)kp[(size_t)(j0 + fn * 16 + l15) * 88 + 64];
      int col = j0 + fn * 16 + l15;
#pragma unroll
      for (int r = 0; r < 4; r++) {
        int row = rt * 16 + l4 * 4 + r;
        float v = sc[fn][r] - qth[r] * ktc;
        s[fn][r] = (!dt || col <= row) ? v : -3e38f;
      }
    }
    float mnew[4], al[4], rs[4];
#pragma unroll
    for (int r = 0; r < 4; r++) {
      float tm = fmaxf(fmaxf(s[0][r], s[1][r]), fmaxf(s[2][r], s[3][r]));
#pragma unroll
      for (int o = 8; o; o >>= 1) tm = fmaxf(tm, __shfl_xor(tm, o));
      mnew[r] = fmaxf(mrun[r], tm);
      al[r] = exp2f((mrun[r] - mnew[r]) * 1.44269504f);
      mrun[r] = mnew[r];
      rs[r] = 0.f;
    }
#pragma unroll
    for (int fn = 0; fn < 4; fn++)
#pragma unroll
      for (int r = 0; r < 4; r++) {
        float pv = exp2f((s[fn][r] - mnew[r]) * 1.44269504f);
        rs[r] += pv;
        sP[(l4 * 4 + r) * 88 + fn * 16 + l15] = (f16)pv;
      }
#pragma unroll
    for (int r = 0; r < 4; r++) {
#pragma unroll
      for (int o = 8; o; o >>= 1) rs[r] += __shfl_xor(rs[r], o);
      lrun[r] = lrun[r] * al[r] + rs[r];
    }
#pragma unroll
    for (int fd = 0; fd < 5; fd++)
#pragma unroll
      for (int r = 0; r < 4; r++) acc[fd][r] *= al[r];
    asm volatile("s_waitcnt lgkmcnt(0)" ::: "memory");
    __builtin_amdgcn_sched_barrier(0);
#pragma unroll
    for (int ks = 0; ks < 2; ks++) {
      f16x8 pf = *(const f16x8*)(sP + l15 * 88 + ks * 32 + l4 * 8);
#pragma unroll
      for (int fd = 0; fd < 5; fd++) {
        f16x8 vf = *(const f16x8*)(vp + (size_t)(fd * 16 + l15) * 1024 + j0 + ks * 32 + l4 * 8);
        acc[fd] = __builtin_amdgcn_mfma_f32_16x16x32_f16(pf, vf, acc[fd], 0, 0, 0);
      }
    }
  }
  const int b = bh >> 3, h = bh & 7;
#pragma unroll
  for (int r = 0; r < 4; r++) {
    float invl = 1.0f / lrun[r];
    float ss = 0.f, ov[4];
#pragma unroll
    for (int fd = 0; fd < 4; fd++) { ov[fd] = acc[fd][r] * invl; ss += ov[fd] * ov[fd]; }
#pragma unroll
    for (int o = 8; o; o >>= 1) ss += __shfl_xor(ss, o);
    float tv = acc[4][r] * invl;
    tv = __shfl(tv, lane & 48);
    float scp = rsqrtf(fmaxf(tv * tv - ss, 1e-6f));
    int row = rt * 16 + l4 * 4 + r;
    size_t rb = ((size_t)b * 1024 + row) * 640 + h * 65;
    if (l15 == 0) st2c(&ao[rb], (f16)(tv * scp));
#pragma unroll
    for (int fd = 0; fd < 4; fd++) st2c(&ao[rb + 1 + fd * 16 + l15], (f16)(ov[fd] * scp));
  }
}

// ---- per-wave residual + l_project (+ optional LN), coherent IO ----
DEV void resproj_row(float (&xreg)[8], int row, const float* rA, const float* rB,
                     const float* rC, const float* rD, int np, const float* bias,
                     float rw, const float* g, const float* bsh, f16* act, int applyLN,
                     float* ssq) {
  const int lane = threadIdx.x & 63, cbase = lane * 8;
  const size_t rb = (size_t)row * 520 + cbase;
  f32x4 a0 = ld16c(rA + rb), a1 = ld16c(rA + rb + 4);
  f32x4 b0 = ld16c(rB + rb), b1 = ld16c(rB + rb + 4);
  f32x4 c0v, c1v, d0, d1;
  if (np == 4) {
    c0v = ld16c(rC + rb); c1v = ld16c(rC + rb + 4);
    d0 = ld16c(rD + rb);  d1 = ld16c(rD + rb + 4);
  }
  vmwait();
  float y[8];
#pragma unroll
  for (int j = 0; j < 4; j++) { y[j] = a0[j] + b0[j]; y[4 + j] = a1[j] + b1[j]; }
  if (np == 4) {
#pragma unroll
    for (int j = 0; j < 4; j++) { y[j] += c0v[j] + d0[j]; y[4 + j] += c1v[j] + d1[j]; }
  }
#pragma unroll
  for (int j = 0; j < 8; j++) {
    int c = cbase + j;
    y[j] = (c >= 1) ? (y[j] + bias[c - 1]) : 0.f;
  }
  float lss = 0.f;
#pragma unroll
  for (int j = 0; j < 8; j++) lss += y[j] * y[j];
  float tax = sqrtf(wsum(lss) + 1.f);
  float u[8];
#pragma unroll
  for (int j = 0; j < 8; j++) u[j] = xreg[j] + rw * y[j];
  if (lane == 0) u[0] = xreg[0] + rw * tax;
  float lsu = 0.f, lsu2 = 0.f;
#pragma unroll
  for (int j = 0; j < 8; j++) { lsu += u[j]; lsu2 += u[j] * u[j]; }
  if (lane == 0) { lsu -= u[0]; lsu2 -= u[0] * u[0]; }
  float su = wsum(lsu), su2 = wsum(lsu2);
  float ut = __shfl(u[0], 0);
  float scp = rsqrtf(fmaxf(ut * ut - su2, 1e-6f));
  float nx[8];
#pragma unroll
  for (int j = 0; j < 8; j++) { nx[j] = u[j] * scp; xreg[j] = nx[j]; }
  if (lane == 0)
    __hip_atomic_store(&ssq[row], 0.f, __ATOMIC_RELAXED, __HIP_MEMORY_SCOPE_AGENT);
  f16* ar = act + (size_t)row * 512;
  f16x8 ov;
  if (applyLN) {
    float mu = su * scp * (1.f / 511.f);
    float var = su2 * scp * scp * (1.f / 511.f) - mu * mu;
    float inv = rsqrtf(var + 1e-5f);
    float n[8], lsn = 0.f;
#pragma unroll
    for (int j = 0; j < 8; j++) {
      int c = cbase + j;
      float nv = (c >= 1) ? ((nx[j] - mu) * inv * g[c - 1] + bsh[c - 1]) : 0.f;
      n[j] = nv; lsn += nv * nv;
    }
    float t2 = sqrtf(wsum(lsn) + 1.f);
    if (lane == 0) n[0] = t2;
#pragma unroll
    for (int j = 0; j < 8; j++) ov[j] = (f16)n[j];
  } else {
#pragma unroll
    for (int j = 0; j < 8; j++) ov[j] = (f16)nx[j];
  }
  st16c(ar + cbase, asf32(ov));
}

DEV void embed_row(float (&xreg)[8], int row, const int* tok, const float* tbl,
                   const float* g, const float* bsh, f16* act, float* ssq) {
  const int lane = threadIdx.x & 63, cbase = lane * 8;
  const float* e = tbl + (size_t)tok[row] * 511;
  float ev[8];
#pragma unroll
  for (int j = 0; j < 8; j++) {
    int c = cbase + j;
    ev[j] = (c >= 1) ? e[c - 1] : 0.f;
  }
  float lss = 0.f, lsu = 0.f;
#pragma unroll
  for (int j = 0; j < 8; j++) { lss += ev[j] * ev[j]; lsu += ev[j]; }
  float ss = wsum(lss), su = wsum(lsu);
  float t = sqrtf(ss + 1.f);
#pragma unroll
  for (int j = 0; j < 8; j++) xreg[j] = ev[j];
  if (lane == 0) xreg[0] = t;
  float mu = su * (1.f / 511.f);
  float var = ss * (1.f / 511.f) - mu * mu;
  float inv = rsqrtf(var + 1e-5f);
  float n[8], lsn = 0.f;
#pragma unroll
  for (int j = 0; j < 8; j++) {
    int c = cbase + j;
    float nv = (c >= 1) ? ((ev[j] - mu) * inv * g[c - 1] + bsh[c - 1]) : 0.f;
    n[j] = nv; lsn += nv * nv;
  }
  float t2 = sqrtf(wsum(lsn) + 1.f);
  if (lane == 0) n[0] = t2;
  f16x8 ov;
#pragma unroll
  for (int j = 0; j < 8; j++) ov[j] = (f16)n[j];
  st16c(act + (size_t)row * 512 + cbase, asf32(ov));
  if (lane == 0)
    __hip_atomic_store(&ssq[row], 0.f, __ATOMIC_RELAXED, __HIP_MEMORY_SCOPE_AGENT);
}

DEV void final_row(int row, const float* raw, const float* bias, const float* g,
                   const float* bsh, float* out) {
  const int lane = threadIdx.x & 63, cbase = lane * 8;
  const size_t rb = (size_t)row * 520 + cbase;
  f32x4 a0 = ld16c(raw + rb), a1 = ld16c(raw + rb + 4);
  vmwait();
  float y[8];
#pragma unroll
  for (int j = 0; j < 4; j++) { y[j] = a0[j]; y[4 + j] = a1[j]; }
  float lss = 0.f, lsu = 0.f;
#pragma unroll
  for (int j = 0; j < 8; j++) {
    int c = cbase + j;
    y[j] = (c >= 1) ? (y[j] + bias[c - 1]) : 0.f;
    lss += y[j] * y[j]; lsu += y[j];
  }
  float s2 = wsum(lss), su = wsum(lsu);
  float mu = su * (1.f / 511.f);
  float var = s2 * (1.f / 511.f) - mu * mu;
  float inv = rsqrtf(var + 1e-5f);
  float n[8], lsn = 0.f;
#pragma unroll
  for (int j = 0; j < 8; j++) {
    int c = cbase + j;
    float nv = (c >= 1) ? ((y[j] - mu) * inv * g[c - 1] + bsh[c - 1]) : 0.f;
    n[j] = nv; lsn += nv * nv;
  }
  float t2 = sqrtf(wsum(lsn) + 1.f);
  if (lane == 0) n[0] = t2;
  float* orow = out + (size_t)row * 512 + cbase;
  f32x4 o0, o1;
#pragma unroll
  for (int j = 0; j < 4; j++) { o0[j] = n[j]; o1[j] = n[4 + j]; }
  *(f32x4*)orow = o0;
  *(f32x4*)(orow + 4) = o1;
}

__global__ __launch_bounds__(512, 2) void k_mega(MP p) {
  const int tid = threadIdx.x, wid = tid >> 6;
  __shared__ __align__(16) char SM[33792];
  __shared__ u32 hdr[4];
  float xreg[8];

  u32 myxcc;
  asm volatile("s_getreg_b32 %0, hwreg(HW_REG_XCC_ID)" : "=s"(myxcc));
  myxcc &= 7;
  if (tid == 0) hdr[0] = inc_rlx(p.bar + 320 + myxcc);
  gbar_init(p.bar);
  if (tid == 0) {
    u32 nx = 0, nxcd = 0, pre = 0;
#pragma unroll
    for (int x = 0; x < 8; x++) {
      u32 c = ld_rlx(p.bar + 320 + x);
      if (c) nxcd++;
      if ((u32)x < myxcc) pre += c;
      if ((u32)x == myxcc) nx = c;
    }
    hdr[1] = nx; hdr[2] = nxcd; hdr[3] = pre;
  }
  __syncthreads();
  const u32 Nx = hdr[1], NXCD = hdr[2];
  const int tt = (int)(hdr[3] + hdr[0]);
  __syncthreads();
  const int myrow = tt * 8 + wid;

  // ---- phase 0: weight transposes (cached) + ao pad + embed ----
  for (int t = tt; t < 9472; t += 256) {
    const float* W; f16* D; int K, N, ldk, n0, k0;
    if (t < 2304) {
      int mat = t >> 6, tile = t & 63;
      int layer = mat / 3, typ = mat % 3;
      W = (typ == 0 ? p.Wq : typ == 1 ? p.Wk : p.Wv) + (size_t)layer * 262144;
      D = p.wqkvT + (size_t)layer * 786432 + (size_t)typ * 262144;
      K = 512; N = 512; ldk = 512; n0 = (tile >> 3) * 64; k0 = (tile & 7) * 64;
    } else if (t < 3264) {
      int id = t - 2304; int l = id / 80, tile = id % 80;
      W = p.Wo + (size_t)l * 265720; D = p.woT + (size_t)l * 327680;
      K = 520; N = 511; ldk = 640; n0 = (tile / 10) * 64; k0 = (tile % 10) * 64;
    } else if (t < 6336) {
      int id = t - 3264; int l = id >> 8, tile = id & 255;
      W = p.Wfc + (size_t)l * 1048064; D = p.wfcT + (size_t)l * 1048576;
      K = 512; N = 2047; ldk = 512; n0 = (tile >> 3) * 64; k0 = (tile & 7) * 64;
    } else if (t < 9408) {
      int id = t - 6336; int l = id >> 8, tile = id & 255;
      W = p.Wpr + (size_t)l * 1046528 + 511; D = p.wprT + (size_t)l * 1048576;
      K = 2047; N = 511; ldk = 2048; n0 = (tile >> 5) * 64; k0 = (tile & 31) * 64;
    } else {
      int id = t - 9408;
      W = p.Wfin; D = p.wfinT; K = 512; N = 511; ldk = 512;
      n0 = (id >> 3) * 64; k0 = (id & 7) * 64;
    }
    trans_tile(W, D, K, N, ldk, n0, k0, SM);
  }
  for (int i = tt * 512 + tid; i < 2048 * 120; i += 256 * 512)
    p.ao[(size_t)(i / 120) * 640 + 520 + (i % 120)] = (f16)0.f;
  embed_row(xreg, myrow, p.tok, p.etab, p.ln1g, p.ln1b, p.actA, p.ssq);
  gbar_heavy(p.bar, myxcc, Nx, NXCD);   // weights now durable+clean in every L2 view

  for (int li = 0; li < 12; li++) {
    const f16* wqkvT_l = p.wqkvT + (size_t)li * 786432;
    const f16* woT_l = p.woT + (size_t)li * 327680;
    const f16* wfcT_l = p.wfcT + (size_t)li * 1048576;
    const f16* wprT_l = p.wprT + (size_t)li * 1048576;
    f16* qhat_l = p.qhat + (size_t)li * 16 * 1024 * 88;
    f16* khat_l = p.khat + (size_t)li * 16 * 1024 * 88;
    f16* vT_l = p.vT + (size_t)li * 16 * 80 * 1024;
    const float* bq_l = p.bq + li * 512;
    const float* bk_l = p.bk + li * 512;
    const float* bv_l = p.bv + li * 512;
    const float* bo_l = p.bo + li * 511;
    const float* bfc_l = p.bfc + li * 2047;
    const float* bpr_l = p.bpr + li * 511;
    const float* w0_l = p.Wpr + (size_t)li * 1046528;

    for (int t = tt; t < 192; t += 256)
      gemm_task<1>(p.actA, wqkvT_l, 512, 512, t / 12, t % 12, 0, 8, nullptr,
                   bq_l, bk_l, bv_l, nullptr, qhat_l, khat_l, vT_l, 0, SM);
    gbar_light(p.bar, myxcc, Nx, NXCD);
    if (wid < 4) {
      int T = wid * 16 + ((wid & 1) ? (15 - (tt >> 4)) : (tt >> 4));
      attn_task(T * 16 + (tt & 15), qhat_l, khat_l, vT_l, p.ao, SM + wid * 2816);
    }
    gbar_light(p.bar, myxcc, Nx, NXCD);
    {
      int t = tt;
      int tm = t >> 4, tn = (t >> 2) & 3, tz = t & 3;
      int kb = (tz == 0) ? 0 : (64 + tz * 128);
      int ksn = (tz == 0) ? 3 : 2;
      float* O = tz == 0 ? p.rawA : tz == 1 ? p.rawB : tz == 2 ? p.rawC : p.rawD;
      gemm_task<0>(p.ao, woT_l, 640, 640, tm, tn, kb, ksn, O,
                   nullptr, nullptr, nullptr, nullptr, nullptr, nullptr, nullptr, 0, SM);
    }
    gbar_light(p.bar, myxcc, Nx, NXCD);
    resproj_row(xreg, myrow, p.rawA, p.rawB, p.rawC, p.rawD, 4, bo_l, p.rw1[li],
                p.ln2g + li * 511, p.ln2b + li * 511, p.actA, 1, p.ssq);
    gbar_light(p.bar, myxcc, Nx, NXCD);
    for (int t = tt; t < 256; t += 256)
      gemm_task<2>(p.actA, wfcT_l, 512, 512, t >> 4, t & 15, 0, 8, nullptr,
                   bfc_l, nullptr, nullptr, p.ssq, p.fcact, nullptr, nullptr, 0, SM);
    gbar_light(p.bar, myxcc, Nx, NXCD);
    for (int t = tt; t < 256; t += 256) {
      int tm = t >> 4, tn = (t >> 2) & 3, tz = t & 3;
      float* O = tz == 0 ? p.rawA : tz == 1 ? p.rawB : tz == 2 ? p.rawC : p.rawD;
      gemm_task<3>(p.fcact, wprT_l, 2048, 2048, tm, tn, tz * 512, 8, O,
                   w0_l, nullptr, nullptr, p.ssq, nullptr, nullptr, nullptr, tz == 0, SM);
    }
    gbar_light(p.bar, myxcc, Nx, NXCD);
    const float* ng = (li < 11) ? p.ln1g + (li + 1) * 511 : p.ln1g;
    const float* nb = (li < 11) ? p.ln1b + (li + 1) * 511 : p.ln1b;
    resproj_row(xreg, myrow, p.rawA, p.rawB, p.rawC, p.rawD, 4, bpr_l, p.rw2[li],
                ng, nb, p.actA, (li < 11) ? 1 : 0, p.ssq);
    gbar_light(p.bar, myxcc, Nx, NXCD);
  }

  for (int t = tt; t < 64; t += 256)
    gemm_task<0>(p.actA, p.wfinT, 512, 512, t >> 2, t & 3, 0, 8, p.rawA,
                 nullptr, nullptr, nullptr, nullptr, nullptr, nullptr, nullptr, 0, SM);
  gbar_light(p.bar, myxcc, Nx, NXCD);
  final_row(myrow, p.rawA, p.bfin, p.lnfg, p.lnfb, p.out);
}

extern "C" void kernel_launch(void* const* d_in, const int* in_sizes, int n_in,
                              void* d_out, int out_size, void* d_ws, size_t ws_size,
                              hipStream_t stream) {
  (void)in_sizes; (void)n_in; (void)out_size; (void)ws_size;
  MP p;
  p.tok = (const int*)d_in[0];
  p.etab = (const float*)d_in[1];
  p.Wq = (const float*)d_in[2];  p.bq = (const float*)d_in[3];
  p.Wk = (const float*)d_in[4];  p.bk = (const float*)d_in[5];
  p.Wv = (const float*)d_in[6];  p.bv = (const float*)d_in[7];
  p.Wo = (const float*)d_in[8];  p.bo = (const float*)d_in[9];
  p.ln1g = (const float*)d_in[10]; p.ln1b = (const float*)d_in[11];
  p.ln2g = (const float*)d_in[12]; p.ln2b = (const float*)d_in[13];
  p.Wfc = (const float*)d_in[14]; p.bfc = (const float*)d_in[15];
  p.Wpr = (const float*)d_in[16]; p.bpr = (const float*)d_in[17];
  p.rw1 = (const float*)d_in[18]; p.rw2 = (const float*)d_in[19];
  p.Wfin = (const float*)d_in[20]; p.bfin = (const float*)d_in[21];
  p.lnfg = (const float*)d_in[22]; p.lnfb = (const float*)d_in[23];

  char* wsb = (char*)d_ws;
  size_t off = 0;
  auto alloc = [&](size_t bytes) -> char* {
    char* q = wsb + off;
    off = (off + bytes + 1023) & ~(size_t)1023;
    return q;
  };
  p.actA = (f16*)alloc(2048ull * 512 * 2);
  p.rawA = (float*)alloc(2048ull * 520 * 4);
  p.rawB = (float*)alloc(2048ull * 520 * 4);
  p.rawC = (float*)alloc(2048ull * 520 * 4);
  p.rawD = (float*)alloc(2048ull * 520 * 4);
  p.ssq = (float*)alloc(2048ull * 4);
  p.qhat = (f16*)alloc(12ull * 16 * 1024 * 88 * 2);
  p.khat = (f16*)alloc(12ull * 16 * 1024 * 88 * 2);
  p.vT = (f16*)alloc(12ull * 16 * 80 * 1024 * 2);
  p.ao = (f16*)alloc(2048ull * 640 * 2);
  p.fcact = (f16*)alloc(2048ull * 2048 * 2);
  p.wqkvT = (f16*)alloc(12ull * 786432 * 2);
  p.woT = (f16*)alloc(12ull * 327680 * 2);
  p.wfcT = (f16*)alloc(12ull * 1048576 * 2);
  p.wprT = (f16*)alloc(12ull * 1048576 * 2);
  p.wfinT = (f16*)alloc(512ull * 512 * 2);
  p.bar = (u32*)alloc(4096);
  p.out = (float*)d_out;

  hipMemsetAsync(p.bar, 0, 4096, stream);
  k_mega<<<256, 512, 0, stream>>>(p);
}

// Round 7
// 2600.701 us; speedup vs baseline: 1.0676x; 1.0676x over previous
//
#include <hip/hip_runtime.h>
#include <cstdint>

typedef _Float16 f16;
typedef _Float16 f16x8 __attribute__((ext_vector_type(8)));
typedef float f32x4 __attribute__((ext_vector_type(4)));
typedef float f32x2 __attribute__((ext_vector_type(2)));
typedef unsigned int u32;

#define DEV __device__ __forceinline__

DEV void gll16(const void* g, void* l) {
  __builtin_amdgcn_global_load_lds((const __attribute__((address_space(1))) u32*)g,
                                   (__attribute__((address_space(3))) u32*)l, 16, 0, 0);
}

// COH=0: sc0 (SE scope: L1-bypass, local-L2 lookup) loads, plain stores.
// COH=1: sc0 sc1 (system scope: LLC) both ways — correct for any placement.
template <int COH> DEV f32x4 ldm16(const void* p) {
  f32x4 r;
  if constexpr (COH)
    asm volatile("global_load_dwordx4 %0, %1, off sc0 sc1" : "=&v"(r) : "v"(p) : "memory");
  else
    asm volatile("global_load_dwordx4 %0, %1, off sc0" : "=&v"(r) : "v"(p) : "memory");
  return r;
}
template <int COH> DEV f32x2 ldm8(const void* p) {
  f32x2 r;
  if constexpr (COH)
    asm volatile("global_load_dwordx2 %0, %1, off sc0 sc1" : "=&v"(r) : "v"(p) : "memory");
  else
    asm volatile("global_load_dwordx2 %0, %1, off sc0" : "=&v"(r) : "v"(p) : "memory");
  return r;
}
template <int COH> DEV void stm16(void* p, f32x4 v) {
  if constexpr (COH)
    asm volatile("global_store_dwordx4 %0, %1, off sc0 sc1" :: "v"(p), "v"(v) : "memory");
  else
    *(f32x4*)p = v;
}
template <int COH> DEV void stm4(void* p, float v) {
  if constexpr (COH)
    asm volatile("global_store_dword %0, %1, off sc0 sc1" :: "v"(p), "v"(v) : "memory");
  else
    *(float*)p = v;
}
template <int COH> DEV void stm2(void* p, f16 v) {
  if constexpr (COH) {
    unsigned short w; __builtin_memcpy(&w, &v, 2);
    u32 ww = w;
    asm volatile("global_store_short %0, %1, off sc0 sc1" :: "v"(p), "v"(ww) : "memory");
  } else
    *(f16*)p = v;
}
// always-coherent (cross-XCD publish): LLC write-through
DEV void st2c(void* p, f16 v) {
  unsigned short w; __builtin_memcpy(&w, &v, 2);
  u32 ww = w;
  asm volatile("global_store_short %0, %1, off sc0 sc1" :: "v"(p), "v"(ww) : "memory");
}
DEV void vmwait() {
  asm volatile("s_waitcnt vmcnt(0)" ::: "memory");
  __builtin_amdgcn_sched_barrier(0);
}
DEV f16x8 asf16(f32x4 v) { f16x8 r; __builtin_memcpy(&r, &v, 16); return r; }
DEV f32x4 asf32(f16x8 v) { f32x4 r; __builtin_memcpy(&r, &v, 16); return r; }

DEV float wsum(float v) {
#pragma unroll
  for (int o = 32; o; o >>= 1) v += __shfl_xor(v, o);
  return v;
}

struct MP {
  const int* tok; const float* etab;
  const float* Wq; const float* bq; const float* Wk; const float* bk;
  const float* Wv; const float* bv; const float* Wo; const float* bo;
  const float* ln1g; const float* ln1b; const float* ln2g; const float* ln2b;
  const float* Wfc; const float* bfc; const float* Wpr; const float* bpr;
  const float* rw1; const float* rw2; const float* Wfin; const float* bfin;
  const float* lnfg; const float* lnfb;
  f16* actA; float* rawA; float* rawB; float* rawC; float* rawD; float* pssq;
  f16* qhat; f16* khat; f16* vT; f16* ao; f16* fcact;
  f16* wqkvT; f16* woT; f16* wfcT; f16* wprT; f16* wfinT;
  u32* bar; float* out;
};

DEV u32 ld_rlx(u32* p) { return __hip_atomic_load(p, __ATOMIC_RELAXED, __HIP_MEMORY_SCOPE_AGENT); }
DEV u32 inc_rlx(u32* p) { return __hip_atomic_fetch_add(p, 1u, __ATOMIC_RELAXED, __HIP_MEMORY_SCOPE_AGENT); }

DEV void gbar_init(u32* bar) {
  __syncthreads();
  if (threadIdx.x == 0) {
    u32* root0 = bar + 352;
    u32* gen0 = bar + 384;
    u32 g = ld_rlx(gen0);
    __builtin_amdgcn_fence(__ATOMIC_RELEASE, "agent");
    u32 a = inc_rlx(root0);
    if ((a & 255u) == 255u) {
      __hip_atomic_store(gen0, g + 1u, __ATOMIC_RELEASE, __HIP_MEMORY_SCOPE_AGENT);
    } else {
      for (int it = 0; it < (1 << 22); ++it) {
        if (ld_rlx(gen0) != g) break;
        __builtin_amdgcn_s_sleep(2);
      }
    }
    __builtin_amdgcn_fence(__ATOMIC_ACQUIRE, "agent");
  }
  __syncthreads();
}

// heavy: once after phase 0 (publishes plain-stored weights to all L2 views)
DEV void gbar_heavy(u32* bar, u32 myxcc, u32 Nx, u32 NXCD) {
  __syncthreads();
  if (threadIdx.x == 0) {
    u32* cnt = bar + 64 + myxcc * 32;
    u32* root = bar + 0;
    u32* gen = bar + 32;
    u32 g = ld_rlx(gen);
    asm volatile("s_waitcnt vmcnt(0) lgkmcnt(0)" ::: "memory");
    u32 a = inc_rlx(cnt);
    bool flipped = false;
    if (a % Nx == Nx - 1u) {
      __builtin_amdgcn_fence(__ATOMIC_RELEASE, "agent");
      asm volatile("s_waitcnt vmcnt(0)" ::: "memory");
      u32 b = inc_rlx(root);
      if (b % NXCD == NXCD - 1u) {
        __hip_atomic_store(gen, g + 1u, __ATOMIC_RELEASE, __HIP_MEMORY_SCOPE_AGENT);
        flipped = true;
      }
    }
    if (!flipped) {
      for (int it = 0; it < (1 << 22); ++it) {
        if (ld_rlx(gen) != g) break;
        __builtin_amdgcn_s_sleep(2);
      }
    }
    __builtin_amdgcn_fence(__ATOMIC_ACQUIRE, "agent");
  }
  __syncthreads();
}

// light: zero cache maintenance (data coherence by construction)
DEV void gbar_light(u32* bar, u32 myxcc, u32 Nx, u32 NXCD) {
  __syncthreads();  // each wave drains its own vmcnt before arriving
  if (threadIdx.x == 0) {
    u32* cnt = bar + 64 + myxcc * 32;
    u32* root = bar + 0;
    u32* gen = bar + 32;
    u32 g = ld_rlx(gen);
    u32 a = inc_rlx(cnt);
    bool flipped = false;
    if (a % Nx == Nx - 1u) {
      u32 b = inc_rlx(root);
      if (b % NXCD == NXCD - 1u) {
        __hip_atomic_store(gen, g + 1u, __ATOMIC_RELAXED, __HIP_MEMORY_SCOPE_AGENT);
        flipped = true;
      }
    }
    if (!flipped) {
      for (int it = 0; it < (1 << 22); ++it) {
        if (ld_rlx(gen) != g) break;
        __builtin_amdgcn_s_sleep(2);
      }
    }
    __builtin_amdgcn_fence(__ATOMIC_ACQUIRE, "workgroup");  // compiler order, no cache inv
  }
  __syncthreads();
}

// ---- 64x64 f32->f16 transpose tile through LDS (phase 0, plain stores) ----
DEV void trans_tile(const float* W, f16* BT, int K, int N, int ldk, int n0, int k0,
                    char* SM) {
  float* tile = (float*)SM;
  const int tid = threadIdx.x;
  const int c = tid & 63, r0 = tid >> 6;
#pragma unroll
  for (int i = 0; i < 8; i++) {
    int kr = r0 + i * 8;
    int k = k0 + kr, n = n0 + c;
    tile[kr * 65 + c] = (k < K && n < N) ? W[(size_t)k * N + n] : 0.f;
  }
  __syncthreads();
#pragma unroll
  for (int i = 0; i < 8; i++) {
    int nn = r0 + i * 8;
    BT[(size_t)(n0 + nn) * ldk + k0 + c] = (f16)tile[c * 65 + nn];
  }
  __syncthreads();
}

// ---- 128x128 GEMM task: A sc0-staged (mutable), B gll16 (immutable weights) ----
template <int EPI, int COH>
DEV void gemm_task(const f16* A, const f16* B, int lda, int ldb, int tm, int tn,
                   int kbeg, int ksteps, float* O, const float* c0, const float* c1,
                   const float* c2, float* pssq, f16* H1, f16* H2, f16* H3,
                   int addR1, char* SM) {
  const int tid = threadIdx.x, wid = tid >> 6, lane = tid & 63;
  const int l15 = lane & 15, l4 = lane >> 4;
  const int wm = wid & 3, wn = wid >> 2;
  const int m0 = tm * 128, n0 = tn * 128;
  f32x4 acc[2][4];
#pragma unroll
  for (int i = 0; i < 2; i++)
#pragma unroll
    for (int j = 0; j < 4; j++) acc[i][j] = (f32x4){0.f, 0.f, 0.f, 0.f};
  const size_t ldab = (size_t)lda * 2, ldbb = (size_t)ldb * 2;
  const int swz = ((lane & 7) ^ (lane >> 3)) * 16;
  const char* Ab = (const char*)A + (size_t)(m0 + (lane >> 3)) * ldab + swz + (size_t)kbeg * 2;
  const char* Bb = (const char*)B + (size_t)(n0 + (lane >> 3)) * ldbb + swz + (size_t)kbeg * 2;
  char* sA0 = SM;            // 2 x 16 KB
  char* sB0 = SM + 32768;    // 2 x 16 KB
  f32x4 a0, a1;
  auto loadA = [&](int ks) {
    a0 = ldm16<COH>(Ab + (size_t)(wid * 8) * ldab + (size_t)ks * 128);
    a1 = ldm16<COH>(Ab + (size_t)((wid + 8) * 8) * ldab + (size_t)ks * 128);
  };
  auto writeA = [&](int buf) {
    *(f32x4*)(sA0 + buf * 16384 + wid * 1024 + lane * 16) = a0;
    *(f32x4*)(sA0 + buf * 16384 + (wid + 8) * 1024 + lane * 16) = a1;
  };
  auto stageB = [&](int buf, int ks) {
    char* db = sB0 + buf * 16384;
    for (int i = wid; i < 16; i += 8) gll16(Bb + (size_t)(i * 8) * ldbb + (size_t)ks * 128, db + i * 1024);
  };
  loadA(0);
  stageB(0, 0);
  asm volatile("s_waitcnt vmcnt(0)" ::: "memory");
  __builtin_amdgcn_sched_barrier(0);
  writeA(0);
  asm volatile("s_waitcnt lgkmcnt(0)" ::: "memory");
  __builtin_amdgcn_s_barrier();
  int cur = 0;
  for (int ks = 0; ks < ksteps; ks++) {
    const bool more = (ks + 1 < ksteps);
    if (more) { loadA(ks + 1); stageB(cur ^ 1, ks + 1); }
    const f16* sA = (const f16*)(sA0 + cur * 16384);
    const f16* sB = (const f16*)(sB0 + cur * 16384);
#pragma unroll
    for (int kk = 0; kk < 2; kk++) {
      f16x8 af[2], bf[4];
#pragma unroll
      for (int i = 0; i < 2; i++) {
        int row = wm * 32 + i * 16 + l15;
        af[i] = *(const f16x8*)(sA + row * 64 + (((kk * 4 + l4) ^ (l15 & 7)) * 8));
      }
#pragma unroll
      for (int j = 0; j < 4; j++) {
        int row = wn * 64 + j * 16 + l15;
        bf[j] = *(const f16x8*)(sB + row * 64 + (((kk * 4 + l4) ^ (l15 & 7)) * 8));
      }
#pragma unroll
      for (int i = 0; i < 2; i++)
#pragma unroll
        for (int j = 0; j < 4; j++)
          acc[i][j] = __builtin_amdgcn_mfma_f32_16x16x32_f16(af[i], bf[j], acc[i][j], 0, 0, 0);
    }
    asm volatile("s_waitcnt vmcnt(0)" ::: "memory");
    __builtin_amdgcn_sched_barrier(0);
    if (more) writeA(cur ^ 1);
    asm volatile("s_waitcnt lgkmcnt(0)" ::: "memory");
    __builtin_amdgcn_s_barrier();
    cur ^= 1;
  }
  if (EPI == 0) {
#pragma unroll
    for (int i = 0; i < 2; i++) {
      int row = m0 + wm * 32 + i * 16 + l4 * 4;
#pragma unroll
      for (int j = 0; j < 4; j++) {
        int col = n0 + wn * 64 + j * 16 + l15;
#pragma unroll
        for (int r = 0; r < 4; r++) stm4<COH>(&O[(size_t)(row + r) * 520 + col + 1], acc[i][j][r]);
      }
    }
  } else if (EPI == 1) {
    const int cb = (n0 >> 6) + wn;
    const int typ = cb >> 3, h = cb & 7;
    const float* bb = (typ == 0) ? c0 : (typ == 1) ? c1 : c2;
    float bj[4];
#pragma unroll
    for (int j = 0; j < 4; j++) bj[j] = bb[h * 64 + j * 16 + l15];
    const float qs = (typ == 0) ? 0.25f : 1.0f;
#pragma unroll
    for (int i = 0; i < 2; i++) {
#pragma unroll
      for (int r = 0; r < 4; r++) {
        float y[4], ss = 0.f;
#pragma unroll
        for (int j = 0; j < 4; j++) { y[j] = acc[i][j][r] + bj[j]; ss += y[j] * y[j]; }
        ss += __shfl_xor(ss, 1); ss += __shfl_xor(ss, 2);
        ss += __shfl_xor(ss, 4); ss += __shfl_xor(ss, 8);
        float t = sqrtf(ss + 1.f);
        int row = m0 + wm * 32 + i * 16 + l4 * 4 + r;
        int b = row >> 10, s = row & 1023, bh = b * 8 + h;
        if (typ < 2) {
          f16* dst = typ ? H2 : H1;
          size_t base = ((size_t)bh * 1024 + s) * 88;
#pragma unroll
          for (int j = 0; j < 4; j++) st2c(&dst[base + j * 16 + l15], (f16)(qs * y[j]));
          if (l15 == 0) st2c(&dst[base + 64], (f16)(qs * t));
        } else {
#pragma unroll
          for (int j = 0; j < 4; j++)
            st2c(&H3[((size_t)bh * 80 + j * 16 + l15) * 1024 + s], (f16)y[j]);
          if (l15 == 0) st2c(&H3[((size_t)bh * 80 + 64) * 1024 + s], (f16)t);
        }
      }
    }
  } else if (EPI == 2) {
#pragma unroll
    for (int i = 0; i < 2; i++) {
#pragma unroll
      for (int r = 0; r < 4; r++) {
        int row = m0 + wm * 32 + i * 16 + l4 * 4 + r;
        float ss = 0.f;
#pragma unroll
        for (int j = 0; j < 4; j++) {
          int col = n0 + wn * 64 + j * 16 + l15;
          float gg = 0.f;
          if (col < 2047) {
            float yv = acc[i][j][r] + c0[col];
            float z = 0.7978845608f * (yv + 0.044715f * yv * yv * yv);
            float th = 1.f - 2.f / (__expf(2.f * z) + 1.f);
            gg = 0.5f * yv * (1.f + th);
          }
          ss += gg * gg;
          stm2<COH>(&H1[(size_t)row * 2048 + col], (f16)gg);
        }
        ss += __shfl_xor(ss, 1); ss += __shfl_xor(ss, 2);
        ss += __shfl_xor(ss, 4); ss += __shfl_xor(ss, 8);
        if (l15 == 0) stm4<COH>(&pssq[(size_t)row * 32 + tn * 2 + wn], ss);
      }
    }
  } else {  // EPI == 3
    float tval[2][4];
    if (addR1) {
      f32x2 pp[2][4];
#pragma unroll
      for (int i = 0; i < 2; i++)
#pragma unroll
        for (int r = 0; r < 4; r++) {
          int row = m0 + wm * 32 + i * 16 + l4 * 4 + r;
          pp[i][r] = ldm8<COH>(&pssq[(size_t)row * 32 + l15 * 2]);
        }
      vmwait();
#pragma unroll
      for (int i = 0; i < 2; i++)
#pragma unroll
        for (int r = 0; r < 4; r++) {
          float s = pp[i][r][0] + pp[i][r][1];
          s += __shfl_xor(s, 1); s += __shfl_xor(s, 2);
          s += __shfl_xor(s, 4); s += __shfl_xor(s, 8);
          tval[i][r] = sqrtf(s + 1.f);
        }
    }
#pragma unroll
    for (int i = 0; i < 2; i++) {
#pragma unroll
      for (int r = 0; r < 4; r++) {
        int row = m0 + wm * 32 + i * 16 + l4 * 4 + r;
#pragma unroll
        for (int j = 0; j < 4; j++) {
          int col = n0 + wn * 64 + j * 16 + l15;
          float v = acc[i][j][r];
          if (addR1) v += tval[i][r] * ((col < 511) ? c0[col] : 0.f);
          stm4<COH>(&O[(size_t)row * 520 + col + 1], v);
        }
      }
    }
  }
}

// ---- per-wave flash attention + l_project (versioned Q/K/V/ao; coherent out) ----
DEV void attn_task(int t, const f16* qhat, const f16* khat, const f16* vT, f16* ao,
                   char* sPb) {
  const int lane = threadIdx.x & 63;
  const int bh = t & 15, rt = 63 - (t >> 4);
  const int l15 = lane & 15, l4 = lane >> 4;
  f16* sP = (f16*)sPb;
  const f16* qp = qhat + ((size_t)bh * 1024 + rt * 16) * 88;
  const f16* kp = khat + (size_t)bh * 1024 * 88;
  const f16* vp = vT + (size_t)bh * 80 * 1024;
  f16x8 qf0 = *(const f16x8*)(qp + l15 * 88 + l4 * 8);
  f16x8 qf1 = *(const f16x8*)(qp + l15 * 88 + 32 + l4 * 8);
  float qth[4];
#pragma unroll
  for (int r = 0; r < 4; r++) qth[r] = (float)qp[(l4 * 4 + r) * 88 + 64];
  f32x4 acc[5];
#pragma unroll
  for (int i = 0; i < 5; i++) acc[i] = (f32x4){0, 0, 0, 0};
  float mrun[4] = {-3e38f, -3e38f, -3e38f, -3e38f}, lrun[4] = {0, 0, 0, 0};
  const int nt = (rt >> 2) + 1;
  for (int jt = 0; jt < nt; ++jt) {
    const int j0 = jt * 64;
    const bool dt = (jt == nt - 1);
    f32x4 sc[4];
#pragma unroll
    for (int fn = 0; fn < 4; fn++) {
      const f16* kb = kp + (size_t)(j0 + fn * 16 + l15) * 88;
      f16x8 k0v = *(const f16x8*)(kb + l4 * 8);
      f16x8 k1v = *(const f16x8*)(kb + 32 + l4 * 8);
      f32x4 a = (f32x4){0, 0, 0, 0};
      a = __builtin_amdgcn_mfma_f32_16x16x32_f16(qf0, k0v, a, 0, 0, 0);
      a = __builtin_amdgcn_mfma_f32_16x16x32_f16(qf1, k1v, a, 0, 0, 0);
      sc[fn] = a;
    }
    float s[4][4];
#pragma unroll
    for (int fn = 0; fn < 4; fn++) {
      float ktc = (float)kp[(size_t)(j0 + fn * 16 + l15) * 88 + 64];
      int col = j0 + fn * 16 + l15;
#pragma unroll
      for (int r = 0; r < 4; r++) {
        int row = rt * 16 + l4 * 4 + r;
        float v = sc[fn][r] - qth[r] * ktc;
        s[fn][r] = (!dt || col <= row) ? v : -3e38f;
      }
    }
    float mnew[4], al[4], rs[4];
#pragma unroll
    for (int r = 0; r < 4; r++) {
      float tm = fmaxf(fmaxf(s[0][r], s[1][r]), fmaxf(s[2][r], s[3][r]));
#pragma unroll
      for (int o = 8; o; o >>= 1) tm = fmaxf(tm, __shfl_xor(tm, o));
      mnew[r] = fmaxf(mrun[r], tm);
      al[r] = exp2f((mrun[r] - mnew[r]) * 1.44269504f);
      mrun[r] = mnew[r];
      rs[r] = 0.f;
    }
#pragma unroll
    for (int fn = 0; fn < 4; fn++)
#pragma unroll
      for (int r = 0; r < 4; r++) {
        float pv = exp2f((s[fn][r] - mnew[r]) * 1.44269504f);
        rs[r] += pv;
        sP[(l4 * 4 + r) * 88 + fn * 16 + l15] = (f16)pv;
      }
#pragma unroll
    for (int r = 0; r < 4; r++) {
#pragma unroll
      for (int o = 8; o; o >>= 1) rs[r] += __shfl_xor(rs[r], o);
      lrun[r] = lrun[r] * al[r] + rs[r];
    }
#pragma unroll
    for (int fd = 0; fd < 5; fd++)
#pragma unroll
      for (int r = 0; r < 4; r++) acc[fd][r] *= al[r];
    asm volatile("s_waitcnt lgkmcnt(0)" ::: "memory");
    __builtin_amdgcn_sched_barrier(0);
#pragma unroll
    for (int ks = 0; ks < 2; ks++) {
      f16x8 pf = *(const f16x8*)(sP + l15 * 88 + ks * 32 + l4 * 8);
#pragma unroll
      for (int fd = 0; fd < 5; fd++) {
        f16x8 vf = *(const f16x8*)(vp + (size_t)(fd * 16 + l15) * 1024 + j0 + ks * 32 + l4 * 8);
        acc[fd] = __builtin_amdgcn_mfma_f32_16x16x32_f16(pf, vf, acc[fd], 0, 0, 0);
      }
    }
  }
  const int b = bh >> 3, h = bh & 7;
#pragma unroll
  for (int r = 0; r < 4; r++) {
    float invl = 1.0f / lrun[r];
    float ss = 0.f, ov[4];
#pragma unroll
    for (int fd = 0; fd < 4; fd++) { ov[fd] = acc[fd][r] * invl; ss += ov[fd] * ov[fd]; }
#pragma unroll
    for (int o = 8; o; o >>= 1) ss += __shfl_xor(ss, o);
    float tv = acc[4][r] * invl;
    tv = __shfl(tv, lane & 48);
    float scp = rsqrtf(fmaxf(tv * tv - ss, 1e-6f));
    int row = rt * 16 + l4 * 4 + r;
    size_t rb = ((size_t)b * 1024 + row) * 576 + h * 65;
    if (l15 == 0) st2c(&ao[rb], (f16)(tv * scp));
#pragma unroll
    for (int fd = 0; fd < 4; fd++) st2c(&ao[rb + 1 + fd * 16 + l15], (f16)(ov[fd] * scp));
  }
}

// ---- per-wave residual + l_project (+ optional LN); row XCD-local ----
template <int COH>
DEV void resproj_row(float (&xreg)[8], int row, const float* rA, const float* rB,
                     const float* rC, const float* rD, const float* bias,
                     float rw, const float* g, const float* bsh, f16* act, int applyLN) {
  const int lane = threadIdx.x & 63, cbase = lane * 8;
  const size_t rb = (size_t)row * 520 + cbase;
  f32x4 a0 = ldm16<COH>(rA + rb), a1 = ldm16<COH>(rA + rb + 4);
  f32x4 b0 = ldm16<COH>(rB + rb), b1 = ldm16<COH>(rB + rb + 4);
  f32x4 c0v = ldm16<COH>(rC + rb), c1v = ldm16<COH>(rC + rb + 4);
  f32x4 d0 = ldm16<COH>(rD + rb), d1 = ldm16<COH>(rD + rb + 4);
  vmwait();
  float y[8];
#pragma unroll
  for (int j = 0; j < 4; j++) {
    y[j] = a0[j] + b0[j] + c0v[j] + d0[j];
    y[4 + j] = a1[j] + b1[j] + c1v[j] + d1[j];
  }
#pragma unroll
  for (int j = 0; j < 8; j++) {
    int c = cbase + j;
    y[j] = (c >= 1) ? (y[j] + bias[c - 1]) : 0.f;
  }
  float lss = 0.f;
#pragma unroll
  for (int j = 0; j < 8; j++) lss += y[j] * y[j];
  float tax = sqrtf(wsum(lss) + 1.f);
  float u[8];
#pragma unroll
  for (int j = 0; j < 8; j++) u[j] = xreg[j] + rw * y[j];
  if (lane == 0) u[0] = xreg[0] + rw * tax;
  float lsu = 0.f, lsu2 = 0.f;
#pragma unroll
  for (int j = 0; j < 8; j++) { lsu += u[j]; lsu2 += u[j] * u[j]; }
  if (lane == 0) { lsu -= u[0]; lsu2 -= u[0] * u[0]; }
  float su = wsum(lsu), su2 = wsum(lsu2);
  float ut = __shfl(u[0], 0);
  float scp = rsqrtf(fmaxf(ut * ut - su2, 1e-6f));
  float nx[8];
#pragma unroll
  for (int j = 0; j < 8; j++) { nx[j] = u[j] * scp; xreg[j] = nx[j]; }
  f16* ar = act + (size_t)row * 512;
  f16x8 ov;
  if (applyLN) {
    float mu = su * scp * (1.f / 511.f);
    float var = su2 * scp * scp * (1.f / 511.f) - mu * mu;
    float inv = rsqrtf(var + 1e-5f);
    float n[8], lsn = 0.f;
#pragma unroll
    for (int j = 0; j < 8; j++) {
      int c = cbase + j;
      float nv = (c >= 1) ? ((nx[j] - mu) * inv * g[c - 1] + bsh[c - 1]) : 0.f;
      n[j] = nv; lsn += nv * nv;
    }
    float t2 = sqrtf(wsum(lsn) + 1.f);
    if (lane == 0) n[0] = t2;
#pragma unroll
    for (int j = 0; j < 8; j++) ov[j] = (f16)n[j];
  } else {
#pragma unroll
    for (int j = 0; j < 8; j++) ov[j] = (f16)nx[j];
  }
  stm16<COH>(ar + cbase, asf32(ov));
}

DEV void embed_row(float (&xreg)[8], int row, const int* tok, const float* tbl,
                   const float* g, const float* bsh, f16* act) {
  const int lane = threadIdx.x & 63, cbase = lane * 8;
  const float* e = tbl + (size_t)tok[row] * 511;
  float ev[8];
#pragma unroll
  for (int j = 0; j < 8; j++) {
    int c = cbase + j;
    ev[j] = (c >= 1) ? e[c - 1] : 0.f;
  }
  float lss = 0.f, lsu = 0.f;
#pragma unroll
  for (int j = 0; j < 8; j++) { lss += ev[j] * ev[j]; lsu += ev[j]; }
  float ss = wsum(lss), su = wsum(lsu);
  float t = sqrtf(ss + 1.f);
#pragma unroll
  for (int j = 0; j < 8; j++) xreg[j] = ev[j];
  if (lane == 0) xreg[0] = t;
  float mu = su * (1.f / 511.f);
  float var = ss * (1.f / 511.f) - mu * mu;
  float inv = rsqrtf(var + 1e-5f);
  float n[8], lsn = 0.f;
#pragma unroll
  for (int j = 0; j < 8; j++) {
    int c = cbase + j;
    float nv = (c >= 1) ? ((ev[j] - mu) * inv * g[c - 1] + bsh[c - 1]) : 0.f;
    n[j] = nv; lsn += nv * nv;
  }
  float t2 = sqrtf(wsum(lsn) + 1.f);
  if (lane == 0) n[0] = t2;
  f16x8 ov;
#pragma unroll
  for (int j = 0; j < 8; j++) ov[j] = (f16)n[j];
  *(f32x4*)(act + (size_t)row * 512 + cbase) = asf32(ov);  // plain: heavy barrier follows
}

template <int COH>
DEV void final_row(int row, const float* raw, const float* bias, const float* g,
                   const float* bsh, float* out) {
  const int lane = threadIdx.x & 63, cbase = lane * 8;
  const size_t rb = (size_t)row * 520 + cbase;
  f32x4 a0 = ldm16<COH>(raw + rb), a1 = ldm16<COH>(raw + rb + 4);
  vmwait();
  float y[8];
#pragma unroll
  for (int j = 0; j < 4; j++) { y[j] = a0[j]; y[4 + j] = a1[j]; }
  float lss = 0.f, lsu = 0.f;
#pragma unroll
  for (int j = 0; j < 8; j++) {
    int c = cbase + j;
    y[j] = (c >= 1) ? (y[j] + bias[c - 1]) : 0.f;
    lss += y[j] * y[j]; lsu += y[j];
  }
  float s2 = wsum(lss), su = wsum(lsu);
  float mu = su * (1.f / 511.f);
  float var = s2 * (1.f / 511.f) - mu * mu;
  float inv = rsqrtf(var + 1e-5f);
  float n[8], lsn = 0.f;
#pragma unroll
  for (int j = 0; j < 8; j++) {
    int c = cbase + j;
    float nv = (c >= 1) ? ((y[j] - mu) * inv * g[c - 1] + bsh[c - 1]) : 0.f;
    n[j] = nv; lsn += nv * nv;
  }
  float t2 = sqrtf(wsum(lsn) + 1.f);
  if (lane == 0) n[0] = t2;
  float* orow = out + (size_t)row * 512 + cbase;
  f32x4 o0, o1;
#pragma unroll
  for (int j = 0; j < 4; j++) { o0[j] = n[j]; o1[j] = n[4 + j]; }
  *(f32x4*)orow = o0;
  *(f32x4*)(orow + 4) = o1;
}

template <int COH>
DEV void run_layers(const MP& p, int tt, u32 myxcc, u32 Nx, u32 NXCD,
                    char* SM, float (&xreg)[8]) {
  const int wid = threadIdx.x >> 6;
  const int xcd = tt >> 5, r = tt & 31;
  const int myrow = tt * 8 + wid;
  for (int li = 0; li < 12; li++) {
    const f16* wqkvT_l = p.wqkvT + (size_t)li * 786432;
    const f16* woT_l = p.woT + (size_t)li * 294912;
    const f16* wfcT_l = p.wfcT + (size_t)li * 1048576;
    const f16* wprT_l = p.wprT + (size_t)li * 1048576;
    f16* qhat_l = p.qhat + (size_t)li * 16 * 1024 * 88;
    f16* khat_l = p.khat + (size_t)li * 16 * 1024 * 88;
    f16* vT_l = p.vT + (size_t)li * 16 * 80 * 1024;
    f16* ao_l = p.ao + (size_t)li * 2048 * 576;
    const float* bq_l = p.bq + li * 512;
    const float* bk_l = p.bk + li * 512;
    const float* bv_l = p.bv + li * 512;
    const float* bo_l = p.bo + li * 511;
    const float* bfc_l = p.bfc + li * 2047;
    const float* bpr_l = p.bpr + li * 511;
    const float* w0_l = p.Wpr + (size_t)li * 1046528;

    if (r < 24) {
      int tm = xcd * 2 + (r >= 12), tn = r % 12;
      gemm_task<1, COH>(p.actA, wqkvT_l, 512, 512, tm, tn, 0, 8, nullptr,
                        bq_l, bk_l, bv_l, nullptr, qhat_l, khat_l, vT_l, 0, SM);
    }
    gbar_light(p.bar, myxcc, Nx, NXCD);
    if (wid < 4) {
      int T = wid * 16 + ((wid & 1) ? (15 - (tt >> 4)) : (tt >> 4));
      attn_task(T * 16 + (tt & 15), qhat_l, khat_l, vT_l, ao_l, SM + wid * 2816);
    }
    gbar_light(p.bar, myxcc, Nx, NXCD);
    {
      int tm = xcd * 2 + (r >> 4), tn = (r >> 2) & 3, tz = r & 3;
      int kbeg = (tz == 0) ? 0 : (192 + (tz - 1) * 128);
      int ksn = (tz == 0) ? 3 : 2;
      float* O = tz == 0 ? p.rawA : tz == 1 ? p.rawB : tz == 2 ? p.rawC : p.rawD;
      gemm_task<0, COH>(ao_l, woT_l, 576, 576, tm, tn, kbeg, ksn, O,
                        nullptr, nullptr, nullptr, nullptr, nullptr, nullptr, nullptr, 0, SM);
    }
    gbar_light(p.bar, myxcc, Nx, NXCD);
    resproj_row<COH>(xreg, myrow, p.rawA, p.rawB, p.rawC, p.rawD, bo_l, p.rw1[li],
                     p.ln2g + li * 511, p.ln2b + li * 511, p.actA, 1);
    gbar_light(p.bar, myxcc, Nx, NXCD);
    {
      int tm = xcd * 2 + (r >> 4), tn = r & 15;
      gemm_task<2, COH>(p.actA, wfcT_l, 512, 512, tm, tn, 0, 8, nullptr,
                        bfc_l, nullptr, nullptr, p.pssq, p.fcact, nullptr, nullptr, 0, SM);
    }
    gbar_light(p.bar, myxcc, Nx, NXCD);
    {
      int tm = xcd * 2 + (r >> 4), tn = (r >> 2) & 3, tz = r & 3;
      float* O = tz == 0 ? p.rawA : tz == 1 ? p.rawB : tz == 2 ? p.rawC : p.rawD;
      gemm_task<3, COH>(p.fcact, wprT_l, 2048, 2048, tm, tn, tz * 512, 8, O,
                        w0_l, nullptr, nullptr, p.pssq, nullptr, nullptr, nullptr, tz == 0, SM);
    }
    gbar_light(p.bar, myxcc, Nx, NXCD);
    const float* ng = (li < 11) ? p.ln1g + (li + 1) * 511 : p.ln1g;
    const float* nb = (li < 11) ? p.ln1b + (li + 1) * 511 : p.ln1b;
    resproj_row<COH>(xreg, myrow, p.rawA, p.rawB, p.rawC, p.rawD, bpr_l, p.rw2[li],
                     ng, nb, p.actA, (li < 11) ? 1 : 0);
    gbar_light(p.bar, myxcc, Nx, NXCD);
  }
  if (r < 8) {
    int tm = xcd * 2 + (r >> 2), tn = r & 3;
    gemm_task<0, COH>(p.actA, p.wfinT, 512, 512, tm, tn, 0, 8, p.rawA,
                      nullptr, nullptr, nullptr, nullptr, nullptr, nullptr, nullptr, 0, SM);
  }
  gbar_light(p.bar, myxcc, Nx, NXCD);
  final_row<COH>(myrow, p.rawA, p.bfin, p.lnfg, p.lnfb, p.out);
}

__global__ __launch_bounds__(512, 2) void k_mega(MP p) {
  const int tid = threadIdx.x, wid = tid >> 6;
  __shared__ __align__(16) char SM[65536];
  __shared__ u32 hdr[5];
  float xreg[8];

  u32 myxcc;
  asm volatile("s_getreg_b32 %0, hwreg(HW_REG_XCC_ID)" : "=s"(myxcc));
  myxcc &= 7;
  if (tid == 0) hdr[0] = inc_rlx(p.bar + 320 + myxcc);
  gbar_init(p.bar);
  if (tid == 0) {
    u32 nx = 0, nxcd = 0, pre = 0, allw = 1;
#pragma unroll
    for (int x = 0; x < 8; x++) {
      u32 c = ld_rlx(p.bar + 320 + x);
      if (c) nxcd++;
      if (c != 32) allw = 0;
      if ((u32)x < myxcc) pre += c;
      if ((u32)x == myxcc) nx = c;
    }
    hdr[1] = nx; hdr[2] = nxcd; hdr[3] = pre; hdr[4] = allw && (nxcd == 8);
  }
  __syncthreads();
  const u32 Nx = hdr[1], NXCD = hdr[2], FASTOK = hdr[4];
  const int tt = (int)(hdr[3] + hdr[0]);
  __syncthreads();
  const int myrow = tt * 8 + wid;

  // ---- phase 0: weight transposes + versioned-ao pad-zero + embed (plain stores) ----
  for (int t = tt; t < 9376; t += 256) {
    const float* W; f16* D; int K, N, ldk, n0, k0;
    if (t < 2304) {
      int mat = t >> 6, tile = t & 63;
      int layer = mat / 3, typ = mat % 3;
      W = (typ == 0 ? p.Wq : typ == 1 ? p.Wk : p.Wv) + (size_t)layer * 262144;
      D = p.wqkvT + (size_t)layer * 786432 + (size_t)typ * 262144;
      K = 512; N = 512; ldk = 512; n0 = (tile >> 3) * 64; k0 = (tile & 7) * 64;
    } else if (t < 3168) {
      int id = t - 2304; int l = id / 72, tile = id % 72;
      W = p.Wo + (size_t)l * 265720; D = p.woT + (size_t)l * 294912;
      K = 520; N = 511; ldk = 576; n0 = (tile / 9) * 64; k0 = (tile % 9) * 64;
    } else if (t < 6240) {
      int id = t - 3168; int l = id >> 8, tile = id & 255;
      W = p.Wfc + (size_t)l * 1048064; D = p.wfcT + (size_t)l * 1048576;
      K = 512; N = 2047; ldk = 512; n0 = (tile >> 3) * 64; k0 = (tile & 7) * 64;
    } else if (t < 9312) {
      int id = t - 6240; int l = id >> 8, tile = id & 255;
      W = p.Wpr + (size_t)l * 1046528 + 511; D = p.wprT + (size_t)l * 1048576;
      K = 2047; N = 511; ldk = 2048; n0 = (tile >> 5) * 64; k0 = (tile & 31) * 64;
    } else {
      int id = t - 9312;
      W = p.Wfin; D = p.wfinT; K = 512; N = 511; ldk = 512;
      n0 = (id >> 3) * 64; k0 = (id & 7) * 64;
    }
    trans_tile(W, D, K, N, ldk, n0, k0, SM);
  }
  {
    f32x4 z = (f32x4){0.f, 0.f, 0.f, 0.f};
    for (int i = tt * 512 + tid; i < 12 * 2048 * 7; i += 256 * 512) {
      int vr = i / 7, c7 = i % 7;
      *(f32x4*)(p.ao + (size_t)vr * 576 + 520 + c7 * 8) = z;
    }
  }
  embed_row(xreg, myrow, p.tok, p.etab, p.ln1g, p.ln1b, p.actA);
  gbar_heavy(p.bar, myxcc, Nx, NXCD);

  if (FASTOK)
    run_layers<0>(p, tt, myxcc, Nx, NXCD, SM, xreg);
  else
    run_layers<1>(p, tt, myxcc, Nx, NXCD, SM, xreg);
}

extern "C" void kernel_launch(void* const* d_in, const int* in_sizes, int n_in,
                              void* d_out, int out_size, void* d_ws, size_t ws_size,
                              hipStream_t stream) {
  (void)in_sizes; (void)n_in; (void)out_size; (void)ws_size;
  MP p;
  p.tok = (const int*)d_in[0];
  p.etab = (const float*)d_in[1];
  p.Wq = (const float*)d_in[2];  p.bq = (const float*)d_in[3];
  p.Wk = (const float*)d_in[4];  p.bk = (const float*)d_in[5];
  p.Wv = (const float*)d_in[6];  p.bv = (const float*)d_in[7];
  p.Wo = (const float*)d_in[8];  p.bo = (const float*)d_in[9];
  p.ln1g = (const float*)d_in[10]; p.ln1b = (const float*)d_in[11];
  p.ln2g = (const float*)d_in[12]; p.ln2b = (const float*)d_in[13];
  p.Wfc = (const float*)d_in[14]; p.bfc = (const float*)d_in[15];
  p.Wpr = (const float*)d_in[16]; p.bpr = (const float*)d_in[17];
  p.rw1 = (const float*)d_in[18]; p.rw2 = (const float*)d_in[19];
  p.Wfin = (const float*)d_in[20]; p.bfin = (const float*)d_in[21];
  p.lnfg = (const float*)d_in[22]; p.lnfb = (const float*)d_in[23];

  char* wsb = (char*)d_ws;
  size_t off = 0;
  auto alloc = [&](size_t bytes) -> char* {
    char* q = wsb + off;
    off = (off + bytes + 1023) & ~(size_t)1023;
    return q;
  };
  p.actA = (f16*)alloc(2048ull * 512 * 2);
  p.rawA = (float*)alloc(2048ull * 520 * 4);
  p.rawB = (float*)alloc(2048ull * 520 * 4);
  p.rawC = (float*)alloc(2048ull * 520 * 4);
  p.rawD = (float*)alloc(2048ull * 520 * 4);
  p.pssq = (float*)alloc(2048ull * 32 * 4);
  p.qhat = (f16*)alloc(12ull * 16 * 1024 * 88 * 2);
  p.khat = (f16*)alloc(12ull * 16 * 1024 * 88 * 2);
  p.vT = (f16*)alloc(12ull * 16 * 80 * 1024 * 2);
  p.ao = (f16*)alloc(12ull * 2048 * 576 * 2);
  p.fcact = (f16*)alloc(2048ull * 2048 * 2);
  p.wqkvT = (f16*)alloc(12ull * 786432 * 2);
  p.woT = (f16*)alloc(12ull * 294912 * 2);
  p.wfcT = (f16*)alloc(12ull * 1048576 * 2);
  p.wprT = (f16*)alloc(12ull * 1048576 * 2);
  p.wfinT = (f16*)alloc(512ull * 512 * 2);
  p.bar = (u32*)alloc(4096);
  p.out = (float*)d_out;

  hipMemsetAsync(p.bar, 0, 4096, stream);
  k_mega<<<256, 512, 0, stream>>>(p);
}

// Round 8
// 1630.232 us; speedup vs baseline: 1.7031x; 1.5953x over previous
//
#include <hip/hip_runtime.h>
#include <cstdint>

typedef _Float16 f16;
typedef _Float16 f16x8 __attribute__((ext_vector_type(8)));
typedef float f32x4 __attribute__((ext_vector_type(4)));
typedef unsigned int u32;

#define DEV __device__ __forceinline__

DEV void gll16(const void* g, void* l) {
  __builtin_amdgcn_global_load_lds((const __attribute__((address_space(1))) u32*)g,
                                   (__attribute__((address_space(3))) u32*)l, 16, 0, 0);
}

DEV float block_sum(float v, float* red) {
#pragma unroll
  for (int o = 32; o; o >>= 1) v += __shfl_xor(v, o);
  int w = threadIdx.x >> 6;
  __syncthreads();
  if ((threadIdx.x & 63) == 0) red[w] = v;
  __syncthreads();
  return red[0] + red[1] + red[2] + red[3];
}

// ---------------- weight transpose+cvt: W[K][N] f32 -> BT[Npad][Kpad] f16, per-layer z ----------------
__global__ void k_trans(const float* __restrict__ W0, f16* __restrict__ BT0, int K, int N, int Kpad,
                        size_t srcStride, size_t dstStride) {
  __shared__ float t[32][33];
  const float* W = W0 + (size_t)blockIdx.z * srcStride;
  f16* BT = BT0 + (size_t)blockIdx.z * dstStride;
  int n0 = blockIdx.x * 32, k0 = blockIdx.y * 32, tx = threadIdx.x, ty = threadIdx.y;
  for (int i = ty; i < 32; i += 8) {
    int k = k0 + i, n = n0 + tx;
    t[i][tx] = (k < K && n < N) ? W[(size_t)k * N + n] : 0.f;
  }
  __syncthreads();
  for (int i = ty; i < 32; i += 8)
    BT[(size_t)(n0 + i) * Kpad + k0 + tx] = (f16)t[tx][i];
}

__global__ void k_trans3(const float* __restrict__ Wq, const float* __restrict__ Wk,
                         const float* __restrict__ Wv, f16* __restrict__ BT) {
  __shared__ float t[32][33];
  const int layer = blockIdx.z / 3, typ = blockIdx.z % 3;
  const float* W = ((typ == 0) ? Wq : (typ == 1) ? Wk : Wv) + (size_t)layer * 262144;
  f16* dst = BT + (size_t)layer * 786432 + (size_t)typ * 262144;
  int n0 = blockIdx.x * 32, k0 = blockIdx.y * 32, tx = threadIdx.x, ty = threadIdx.y;
  for (int i = ty; i < 32; i += 8) t[i][tx] = W[(size_t)(k0 + i) * 512 + n0 + tx];
  __syncthreads();
  for (int i = ty; i < 32; i += 8) dst[(size_t)(n0 + i) * 512 + k0 + tx] = (f16)t[tx][i];
}

// ---------------- GEMM: BK=64, dbuf LDS, raw s_barrier + counted vmcnt ----------------
// EPI 0: O1[row*ldc+col]=acc
// EPI 1: QKV epilogue -> qhat(H1)/khat(H2)/vT(H3)   (BM=128)
// EPI 2: bias+gelu -> H1 f16 [M][2048], atomicAdd ssq (BM=128)
// EPI 3: O(tz) partial; tz==0 adds rank-1 t(ssq)*c0  (BM=64, KZ=4)
template <int BM, int BN, int KZ, int EPI>
__global__ __launch_bounds__((BM == 128) ? 512 : 256)
void k_gemm(const f16* __restrict__ A, const f16* __restrict__ B,
            int lda, int ldb, int klen, int GM,
            float* __restrict__ O1, float* __restrict__ O2,
            float* __restrict__ O3, float* __restrict__ O4, int ldc,
            const float* __restrict__ c0, const float* __restrict__ c1,
            const float* __restrict__ c2, float* __restrict__ ssq,
            f16* __restrict__ H1, f16* __restrict__ H2, f16* __restrict__ H3) {
  constexpr int NW = (BM == 128) ? 8 : 4;      // waves
  constexpr int WM = (BM == 128) ? 4 : 2;      // waves along M
  constexpr int FN = BN / ((NW / WM) * 16);    // col frags per wave
  const int tid = threadIdx.x, wid = tid >> 6, lane = tid & 63;
  const int l15 = lane & 15, l4 = lane >> 4;
  const int wm = wid % WM, wn = wid / WM;
  // XCD-chunked bijective swizzle (gridDim.x % 8 == 0 for all our launches)
  const int nwg = gridDim.x;
  int lin = blockIdx.x;
  int wg = (lin & 7) * (nwg >> 3) + (lin >> 3);
  int tn = wg / (GM * KZ);
  int rem = wg - tn * (GM * KZ);
  int tm = rem / KZ, tz = rem - (rem / KZ) * KZ;
  const int m0 = tm * BM, n0 = tn * BN, kbeg = tz * klen, ksteps = klen / 64;
  __shared__ __align__(16) char SM[(BM + BN) * 256];
  f32x4 acc[2][FN];
#pragma unroll
  for (int i = 0; i < 2; i++)
#pragma unroll
    for (int j = 0; j < FN; j++) acc[i][j] = (f32x4){0.f, 0.f, 0.f, 0.f};
  const size_t ldab = (size_t)lda * 2, ldbb = (size_t)ldb * 2;
  const int swz = ((lane & 7) ^ (lane >> 3)) * 16;
  const char* Ab = (const char*)A + (size_t)(m0 + (lane >> 3)) * ldab + swz + (size_t)kbeg * 2;
  const char* Bb = (const char*)B + (size_t)(n0 + (lane >> 3)) * ldbb + swz + (size_t)kbeg * 2;
  auto stage = [&](int buf, int ks) {  // 4 gll16 per wave
    char* da = SM + buf * (BM * 128);
    char* db = SM + 2 * BM * 128 + buf * (BN * 128);
    for (int i = wid; i < BM / 8; i += NW)
      gll16(Ab + (size_t)(i * 8) * ldab + (size_t)ks * 128, da + i * 1024);
    for (int i = wid; i < BN / 8; i += NW)
      gll16(Bb + (size_t)(i * 8) * ldbb + (size_t)ks * 128, db + i * 1024);
  };
  stage(0, 0);
  asm volatile("s_waitcnt vmcnt(0)" ::: "memory");
  __builtin_amdgcn_s_barrier();
  __builtin_amdgcn_sched_barrier(0);
  int cur = 0;
  for (int ks = 0; ks < ksteps; ks++) {
    const bool more = (ks + 1 < ksteps);
    if (more) {
      stage(cur ^ 1, ks + 1);
      asm volatile("s_waitcnt vmcnt(4)" ::: "memory");  // only cur's 4 loads done
    } else {
      asm volatile("s_waitcnt vmcnt(0)" ::: "memory");
    }
    __builtin_amdgcn_s_barrier();
    __builtin_amdgcn_sched_barrier(0);
    const f16* sA = (const f16*)(SM + cur * (BM * 128));
    const f16* sB = (const f16*)(SM + 2 * BM * 128 + cur * (BN * 128));
#pragma unroll
    for (int kk = 0; kk < 2; kk++) {
      f16x8 af[2], bf[FN];
#pragma unroll
      for (int i = 0; i < 2; i++) {
        int row = wm * 32 + i * 16 + l15;
        af[i] = *(const f16x8*)(sA + row * 64 + (((kk * 4 + l4) ^ (l15 & 7)) * 8));
      }
#pragma unroll
      for (int j = 0; j < FN; j++) {
        int row = wn * (FN * 16) + j * 16 + l15;
        bf[j] = *(const f16x8*)(sB + row * 64 + (((kk * 4 + l4) ^ (l15 & 7)) * 8));
      }
#pragma unroll
      for (int i = 0; i < 2; i++)
#pragma unroll
        for (int j = 0; j < FN; j++)
          acc[i][j] = __builtin_amdgcn_mfma_f32_16x16x32_f16(af[i], bf[j], acc[i][j], 0, 0, 0);
    }
    __builtin_amdgcn_sched_barrier(0);
    __builtin_amdgcn_s_barrier();
    cur ^= 1;
  }
  // ---- epilogues ----
  if (EPI == 0) {
#pragma unroll
    for (int i = 0; i < 2; i++) {
      int row0 = m0 + wm * 32 + i * 16 + l4 * 4;
#pragma unroll
      for (int j = 0; j < FN; j++) {
        int col = n0 + wn * (FN * 16) + j * 16 + l15;
#pragma unroll
        for (int r = 0; r < 4; r++) O1[(size_t)(row0 + r) * ldc + col] = acc[i][j][r];
      }
    }
  } else if (EPI == 1) {
    const int cb = (n0 >> 6) + wn;  // 0..23
    const int typ = cb >> 3, h = cb & 7;
    const float* bb = (typ == 0) ? c0 : (typ == 1) ? c1 : c2;
    float bj[FN];
#pragma unroll
    for (int j = 0; j < FN; j++) bj[j] = bb[h * 64 + j * 16 + l15];
    const float qs = (typ == 0) ? 0.25f : 1.0f;
#pragma unroll
    for (int i = 0; i < 2; i++) {
#pragma unroll
      for (int r = 0; r < 4; r++) {
        float y[FN], ss = 0.f;
#pragma unroll
        for (int j = 0; j < FN; j++) { y[j] = acc[i][j][r] + bj[j]; ss += y[j] * y[j]; }
        ss += __shfl_xor(ss, 1); ss += __shfl_xor(ss, 2);
        ss += __shfl_xor(ss, 4); ss += __shfl_xor(ss, 8);
        float t = sqrtf(ss + 1.f);
        int row = m0 + wm * 32 + i * 16 + l4 * 4 + r;
        int b = row >> 10, s = row & 1023, bh = b * 8 + h;
        if (typ < 2) {
          f16* dst = typ ? H2 : H1;
          size_t base = ((size_t)bh * 1024 + s) * 88;
#pragma unroll
          for (int j = 0; j < FN; j++) dst[base + j * 16 + l15] = (f16)(qs * y[j]);
          if (l15 == 0) dst[base + 64] = (f16)(qs * t);
        } else {
#pragma unroll
          for (int j = 0; j < FN; j++)
            H3[((size_t)bh * 80 + j * 16 + l15) * 1024 + s] = (f16)y[j];
          if (l15 == 0) H3[((size_t)bh * 80 + 64) * 1024 + s] = (f16)t;
        }
      }
    }
  } else if (EPI == 2) {
#pragma unroll
    for (int i = 0; i < 2; i++) {
#pragma unroll
      for (int r = 0; r < 4; r++) {
        int row = m0 + wm * 32 + i * 16 + l4 * 4 + r;
        float ss = 0.f;
#pragma unroll
        for (int j = 0; j < FN; j++) {
          int col = n0 + wn * (FN * 16) + j * 16 + l15;
          float gg = 0.f;
          if (col < 2047) {
            float yv = acc[i][j][r] + c0[col];
            float cc = yv * yv * yv;
            gg = 0.5f * yv * (1.f + tanhf(0.7978845608f * (yv + 0.044715f * cc)));
          }
          ss += gg * gg;
          H1[(size_t)row * 2048 + col] = (f16)gg;
        }
        ss += __shfl_xor(ss, 1); ss += __shfl_xor(ss, 2);
        ss += __shfl_xor(ss, 4); ss += __shfl_xor(ss, 8);
        if (l15 == 0) atomicAdd(ssq + row, ss);
      }
    }
  } else {  // EPI == 3
    float* O = (tz == 0) ? O1 : (tz == 1) ? O2 : (tz == 2) ? O3 : O4;
#pragma unroll
    for (int i = 0; i < 2; i++) {
#pragma unroll
      for (int r = 0; r < 4; r++) {
        int row = m0 + wm * 32 + i * 16 + l4 * 4 + r;
        float t = 0.f;
        if (tz == 0) t = sqrtf(ssq[row] + 1.f);
#pragma unroll
        for (int j = 0; j < FN; j++) {
          int col = n0 + wn * (FN * 16) + j * 16 + l15;
          float v = acc[i][j][r];
          if (tz == 0) v += t * ((col < 511) ? c0[col] : 0.f);
          O[(size_t)row * ldc + col] = v;
        }
      }
    }
  }
}

// ---------------- embed + add_time + LN1 ----------------
__global__ void k_embed(const int* __restrict__ tok, const float* __restrict__ tbl,
                        const float* __restrict__ g, const float* __restrict__ bsh,
                        float* __restrict__ x, f16* __restrict__ act) {
  __shared__ float red[4];
  const int m = blockIdx.x, tid = threadIdx.x;
  const float* e = tbl + (size_t)tok[m] * 511;
  float e0 = (tid < 511) ? e[tid] : 0.f;
  float e1 = (tid + 256 < 511) ? e[tid + 256] : 0.f;
  float s1 = block_sum(e0 + e1, red);
  float s2 = block_sum(e0 * e0 + e1 * e1, red);
  float t = sqrtf(s2 + 1.f);
  float* xr = x + (size_t)m * 512;
  if (tid == 0) xr[0] = t;
  if (tid < 511) xr[1 + tid] = e0;
  if (tid + 256 < 511) xr[257 + tid] = e1;
  float mu = s1 / 511.f;
  float var = s2 / 511.f - mu * mu;
  float inv = rsqrtf(var + 1e-5f);
  float n0 = (tid < 511) ? (e0 - mu) * inv * g[tid] + bsh[tid] : 0.f;
  float n1 = (tid + 256 < 511) ? (e1 - mu) * inv * g[tid + 256] + bsh[tid + 256] : 0.f;
  float sn = block_sum(n0 * n0 + n1 * n1, red);
  float t2 = sqrtf(sn + 1.f);
  f16* ar = act + (size_t)m * 512;
  if (tid == 0) ar[0] = (f16)t2;
  if (tid < 511) ar[1 + tid] = (f16)n0;
  if (tid + 256 < 511) ar[257 + tid] = (f16)n1;
}

// ---------------- per-wave flash attention + l_project ----------------
__launch_bounds__(64)
__global__ void k_attn(const f16* __restrict__ qhat, const f16* __restrict__ khat,
                       const f16* __restrict__ vT, f16* __restrict__ ao) {
  __shared__ f16 sP[16 * 88];
  // XCD-chunked: each XCD chunk of 128 blocks = 2 heads, rt heaviest-first
  const int lin = blockIdx.x;
  const int wg = (lin & 7) * 128 + (lin >> 3);
  const int bh = wg >> 6, rt = 63 - (wg & 63);
  const int lane = threadIdx.x, l15 = lane & 15, l4 = lane >> 4;
  const f16* qp = qhat + ((size_t)bh * 1024 + rt * 16) * 88;
  const f16* kp = khat + (size_t)bh * 1024 * 88;
  const f16* vp = vT + (size_t)bh * 80 * 1024;
  f16x8 qf0 = *(const f16x8*)(qp + l15 * 88 + l4 * 8);
  f16x8 qf1 = *(const f16x8*)(qp + l15 * 88 + 32 + l4 * 8);
  float qth[4];
#pragma unroll
  for (int r = 0; r < 4; r++) qth[r] = (float)qp[(l4 * 4 + r) * 88 + 64];
  f32x4 acc[5];
#pragma unroll
  for (int i = 0; i < 5; i++) acc[i] = (f32x4){0, 0, 0, 0};
  float mrun[4] = {-3e38f, -3e38f, -3e38f, -3e38f}, lrun[4] = {0, 0, 0, 0};
  const int nt = (rt >> 2) + 1;
  for (int jt = 0; jt < nt; ++jt) {
    const int j0 = jt * 64;
    const bool dt = (jt == nt - 1);
    f32x4 sc[4];
#pragma unroll
    for (int fn = 0; fn < 4; fn++) {
      const f16* kb = kp + (size_t)(j0 + fn * 16 + l15) * 88;
      f16x8 k0v = *(const f16x8*)(kb + l4 * 8);
      f16x8 k1v = *(const f16x8*)(kb + 32 + l4 * 8);
      f32x4 a = (f32x4){0, 0, 0, 0};
      a = __builtin_amdgcn_mfma_f32_16x16x32_f16(qf0, k0v, a, 0, 0, 0);
      a = __builtin_amdgcn_mfma_f32_16x16x32_f16(qf1, k1v, a, 0, 0, 0);
      sc[fn] = a;
    }
    float s[4][4];
#pragma unroll
    for (int fn = 0; fn < 4; fn++) {
      float ktc = (float)kp[(size_t)(j0 + fn * 16 + l15) * 88 + 64];
      int col = j0 + fn * 16 + l15;
#pragma unroll
      for (int r = 0; r < 4; r++) {
        int row = rt * 16 + l4 * 4 + r;
        float v = sc[fn][r] - qth[r] * ktc;
        s[fn][r] = (!dt || col <= row) ? v : -3e38f;
      }
    }
    float mnew[4], al[4], rs[4];
#pragma unroll
    for (int r = 0; r < 4; r++) {
      float t = fmaxf(fmaxf(s[0][r], s[1][r]), fmaxf(s[2][r], s[3][r]));
#pragma unroll
      for (int o = 8; o; o >>= 1) t = fmaxf(t, __shfl_xor(t, o));
      mnew[r] = fmaxf(mrun[r], t);
      al[r] = exp2f((mrun[r] - mnew[r]) * 1.44269504f);
      mrun[r] = mnew[r];
      rs[r] = 0.f;
    }
#pragma unroll
    for (int fn = 0; fn < 4; fn++)
#pragma unroll
      for (int r = 0; r < 4; r++) {
        float p = exp2f((s[fn][r] - mnew[r]) * 1.44269504f);
        rs[r] += p;
        sP[(l4 * 4 + r) * 88 + fn * 16 + l15] = (f16)p;
      }
#pragma unroll
    for (int r = 0; r < 4; r++) {
#pragma unroll
      for (int o = 8; o; o >>= 1) rs[r] += __shfl_xor(rs[r], o);
      lrun[r] = lrun[r] * al[r] + rs[r];
    }
#pragma unroll
    for (int fd = 0; fd < 5; fd++)
#pragma unroll
      for (int r = 0; r < 4; r++) acc[fd][r] *= al[r];
    asm volatile("s_waitcnt lgkmcnt(0)" ::: "memory");
    __builtin_amdgcn_sched_barrier(0);
#pragma unroll
    for (int ks = 0; ks < 2; ks++) {
      f16x8 pf = *(const f16x8*)(sP + l15 * 88 + ks * 32 + l4 * 8);
#pragma unroll
      for (int fd = 0; fd < 5; fd++) {
        f16x8 vf = *(const f16x8*)(vp + (size_t)(fd * 16 + l15) * 1024 + j0 + ks * 32 + l4 * 8);
        acc[fd] = __builtin_amdgcn_mfma_f32_16x16x32_f16(pf, vf, acc[fd], 0, 0, 0);
      }
    }
  }
  const int b = bh >> 3, h = bh & 7;
#pragma unroll
  for (int r = 0; r < 4; r++) {
    float invl = 1.0f / lrun[r];
    float ss = 0.f, ov[4];
#pragma unroll
    for (int fd = 0; fd < 4; fd++) { ov[fd] = acc[fd][r] * invl; ss += ov[fd] * ov[fd]; }
#pragma unroll
    for (int o = 8; o; o >>= 1) ss += __shfl_xor(ss, o);
    float tv = acc[4][r] * invl;
    tv = __shfl(tv, lane & 48);
    float scp = rsqrtf(fmaxf(tv * tv - ss, 1e-6f));
    int row = rt * 16 + l4 * 4 + r;
    size_t rowbase = ((size_t)b * 1024 + row) * 576;
    size_t rb = rowbase + h * 65;
    if (l15 == 0) ao[rb] = (f16)(tv * scp);
#pragma unroll
    for (int fd = 0; fd < 4; fd++) ao[rb + 1 + fd * 16 + l15] = (f16)(ov[fd] * scp);
    for (int c = l15; c < 56; c += 16) ao[rowbase + 520 + c] = (f16)0.f;
  }
}

// ---------------- residual + l_project (+ optional LN), zeros ssq ----------------
__global__ void k_resproj(float* __restrict__ x, const float* __restrict__ r1,
                          const float* __restrict__ r2, const float* __restrict__ r3,
                          const float* __restrict__ r4, int np,
                          const float* __restrict__ bias, const float* __restrict__ resw, int li,
                          const float* __restrict__ g, const float* __restrict__ bsh,
                          f16* __restrict__ act, int applyLN, float* __restrict__ ssq) {
  __shared__ float red[4];
  const int m = blockIdx.x, tid = threadIdx.x;
  const size_t rb = (size_t)m * 512;
  float* xr = x + rb;
  const float rw = resw[li];
  if (tid == 0) ssq[m] = 0.f;
  float y0 = 0.f, y1 = 0.f;
  if (tid < 511) {
    y0 = r1[rb + tid];
    if (np == 4) y0 += r2[rb + tid] + r3[rb + tid] + r4[rb + tid];
    y0 += bias[tid];
  }
  if (tid + 256 < 511) {
    y1 = r1[rb + tid + 256];
    if (np == 4) y1 += r2[rb + tid + 256] + r3[rb + tid + 256] + r4[rb + tid + 256];
    y1 += bias[tid + 256];
  }
  float s2 = block_sum(y0 * y0 + y1 * y1, red);
  float tax = sqrtf(s2 + 1.f);
  float xt = xr[0];
  float u0 = (tid < 511) ? xr[1 + tid] + rw * y0 : 0.f;
  float u1 = (tid + 256 < 511) ? xr[257 + tid] + rw * y1 : 0.f;
  float ut = xt + rw * tax;
  float su = block_sum(u0 + u1, red);
  float su2 = block_sum(u0 * u0 + u1 * u1, red);
  float scp = rsqrtf(fmaxf(ut * ut - su2, 1e-6f));
  float nx0 = u0 * scp, nx1 = u1 * scp, nxt = ut * scp;
  if (tid == 0) xr[0] = nxt;
  if (tid < 511) xr[1 + tid] = nx0;
  if (tid + 256 < 511) xr[257 + tid] = nx1;
  f16* ar = act + rb;
  if (applyLN) {
    float mu = su * scp / 511.f;
    float var = su2 * scp * scp / 511.f - mu * mu;
    float inv = rsqrtf(var + 1e-5f);
    float n0 = (tid < 511) ? (nx0 - mu) * inv * g[tid] + bsh[tid] : 0.f;
    float n1 = (tid + 256 < 511) ? (nx1 - mu) * inv * g[tid + 256] + bsh[tid + 256] : 0.f;
    float sn = block_sum(n0 * n0 + n1 * n1, red);
    float t2 = sqrtf(sn + 1.f);
    if (tid == 0) ar[0] = (f16)t2;
    if (tid < 511) ar[1 + tid] = (f16)n0;
    if (tid + 256 < 511) ar[257 + tid] = (f16)n1;
  } else {
    if (tid == 0) ar[0] = (f16)nxt;
    if (tid < 511) ar[1 + tid] = (f16)nx0;
    if (tid + 256 < 511) ar[257 + tid] = (f16)nx1;
  }
}

// ---------------- final bias + LN -> out ----------------
__global__ void k_final(const float* __restrict__ raw, const float* __restrict__ bias,
                        const float* __restrict__ g, const float* __restrict__ bsh,
                        float* __restrict__ out) {
  __shared__ float red[4];
  const int m = blockIdx.x, tid = threadIdx.x;
  const float* rr = raw + (size_t)m * 512;
  float y0 = (tid < 511) ? rr[tid] + bias[tid] : 0.f;
  float y1 = (tid + 256 < 511) ? rr[tid + 256] + bias[tid + 256] : 0.f;
  float s1 = block_sum(y0 + y1, red);
  float s2 = block_sum(y0 * y0 + y1 * y1, red);
  float mu = s1 / 511.f;
  float var = s2 / 511.f - mu * mu;
  float inv = rsqrtf(var + 1e-5f);
  float n0 = (tid < 511) ? (y0 - mu) * inv * g[tid] + bsh[tid] : 0.f;
  float n1 = (tid + 256 < 511) ? (y1 - mu) * inv * g[tid + 256] + bsh[tid + 256] : 0.f;
  float sn = block_sum(n0 * n0 + n1 * n1, red);
  float t2 = sqrtf(sn + 1.f);
  float* orow = out + (size_t)m * 512;
  if (tid == 0) orow[0] = t2;
  if (tid < 511) orow[1 + tid] = n0;
  if (tid + 256 < 511) orow[257 + tid] = n1;
}

extern "C" void kernel_launch(void* const* d_in, const int* in_sizes, int n_in,
                              void* d_out, int out_size, void* d_ws, size_t ws_size,
                              hipStream_t stream) {
  (void)in_sizes; (void)n_in; (void)out_size; (void)ws_size;
  const int* tok = (const int*)d_in[0];
  const float* etab = (const float*)d_in[1];
  const float* Wq = (const float*)d_in[2];
  const float* bq = (const float*)d_in[3];
  const float* Wk = (const float*)d_in[4];
  const float* bk = (const float*)d_in[5];
  const float* Wv = (const float*)d_in[6];
  const float* bv = (const float*)d_in[7];
  const float* Wo = (const float*)d_in[8];
  const float* bo = (const float*)d_in[9];
  const float* ln1g = (const float*)d_in[10];
  const float* ln1b = (const float*)d_in[11];
  const float* ln2g = (const float*)d_in[12];
  const float* ln2b = (const float*)d_in[13];
  const float* Wfc = (const float*)d_in[14];
  const float* bfc = (const float*)d_in[15];
  const float* Wpr = (const float*)d_in[16];
  const float* bpr = (const float*)d_in[17];
  const float* rw1 = (const float*)d_in[18];
  const float* rw2 = (const float*)d_in[19];
  const float* Wfin = (const float*)d_in[20];
  const float* bfin = (const float*)d_in[21];
  const float* lnfg = (const float*)d_in[22];
  const float* lnfb = (const float*)d_in[23];

  char* wsb = (char*)d_ws;
  size_t off = 0;
  auto alloc = [&](size_t bytes) -> char* {
    char* p = wsb + off;
    off = (off + bytes + 1023) & ~(size_t)1023;
    return p;
  };
  float* x = (float*)alloc(2048ull * 512 * 4);
  f16* actA = (f16*)alloc(2048ull * 512 * 2);
  float* raw1 = (float*)alloc(2048ull * 512 * 4);
  float* raw2 = (float*)alloc(2048ull * 512 * 4);
  float* raw3 = (float*)alloc(2048ull * 512 * 4);
  float* raw4 = (float*)alloc(2048ull * 512 * 4);
  float* ssq = (float*)alloc(2048ull * 4);
  f16* qhat = (f16*)alloc(16ull * 1024 * 88 * 2);
  f16* khat = (f16*)alloc(16ull * 1024 * 88 * 2);
  f16* vT = (f16*)alloc(16ull * 80 * 1024 * 2);
  f16* ao = (f16*)alloc(2048ull * 576 * 2);
  f16* fcact = (f16*)alloc(2048ull * 2048 * 2);
  f16* wqkvT = (f16*)alloc(12ull * 1536 * 512 * 2);
  f16* woT = (f16*)alloc(12ull * 512 * 576 * 2);
  f16* wfcT = (f16*)alloc(12ull * 2048 * 512 * 2);
  f16* wprT = (f16*)alloc(12ull * 512 * 2048 * 2);
  f16* wfinT = (f16*)alloc(512ull * 512 * 2);

  // ---- weight transposes hoisted ----
  k_trans3<<<dim3(16, 16, 36), dim3(32, 8), 0, stream>>>(Wq, Wk, Wv, wqkvT);
  k_trans<<<dim3(16, 18, 12), dim3(32, 8), 0, stream>>>(Wo, woT, 520, 511, 576,
                                                        520ull * 511, 512ull * 576);
  k_trans<<<dim3(64, 16, 12), dim3(32, 8), 0, stream>>>(Wfc, wfcT, 512, 2047, 512,
                                                        512ull * 2047, 2048ull * 512);
  k_trans<<<dim3(16, 64, 12), dim3(32, 8), 0, stream>>>(Wpr + 511, wprT, 2047, 511, 2048,
                                                        2048ull * 511, 512ull * 2048);
  k_trans<<<dim3(16, 16, 1), dim3(32, 8), 0, stream>>>(Wfin, wfinT, 512, 511, 512, 0, 0);

  k_embed<<<2048, 256, 0, stream>>>(tok, etab, ln1g, ln1b, x, actA);

  for (int li = 0; li < 12; li++) {
    const f16* wqkvT_l = wqkvT + (size_t)li * 1536 * 512;
    const f16* woT_l = woT + (size_t)li * 512 * 576;
    const f16* wfcT_l = wfcT + (size_t)li * 2048 * 512;
    const f16* wprT_l = wprT + (size_t)li * 512 * 2048;
    const float* Wpr_l = Wpr + (size_t)li * 2048 * 511;
    const float* bq_l = bq + (size_t)li * 512;
    const float* bk_l = bk + (size_t)li * 512;
    const float* bv_l = bv + (size_t)li * 512;
    const float* bo_l = bo + (size_t)li * 511;
    const float* bfc_l = bfc + (size_t)li * 2047;
    const float* bpr_l = bpr + (size_t)li * 511;
    const float* ln2g_l = ln2g + (size_t)li * 511;
    const float* ln2b_l = ln2b + (size_t)li * 511;

    // QKV: M=2048 N=1536 K=512, 128^2, 192 blocks x 512thr
    k_gemm<128, 128, 1, 1><<<192, 512, 0, stream>>>(
        actA, wqkvT_l, 512, 512, 512, 16, nullptr, nullptr, nullptr, nullptr, 0,
        bq_l, bk_l, bv_l, nullptr, qhat, khat, vT);
    k_attn<<<1024, 64, 0, stream>>>(qhat, khat, vT, ao);
    // Wo: M=2048 N=512 K=576, 64^2, 256 blocks
    k_gemm<64, 64, 1, 0><<<256, 256, 0, stream>>>(
        ao, woT_l, 576, 576, 576, 32, raw1, nullptr, nullptr, nullptr, 512,
        nullptr, nullptr, nullptr, nullptr, nullptr, nullptr, nullptr);
    k_resproj<<<2048, 256, 0, stream>>>(x, raw1, raw1, raw1, raw1, 1, bo_l, rw1, li,
                                        ln2g_l, ln2b_l, actA, 1, ssq);
    // FC: M=2048 N=2048 K=512, 128^2, 256 blocks x 512thr
    k_gemm<128, 128, 1, 2><<<256, 512, 0, stream>>>(
        actA, wfcT_l, 512, 512, 512, 16, nullptr, nullptr, nullptr, nullptr, 0,
        bfc_l, nullptr, nullptr, ssq, fcact, nullptr, nullptr);
    // Wpr: M=2048 N=512 K=2048, 64^2, split-K 4, 1024 blocks
    k_gemm<64, 64, 4, 3><<<1024, 256, 0, stream>>>(
        fcact, wprT_l, 2048, 2048, 512, 32, raw1, raw2, raw3, raw4, 512,
        Wpr_l, nullptr, nullptr, ssq, nullptr, nullptr, nullptr);
    const float* ng = (li < 11) ? ln1g + (size_t)(li + 1) * 511 : ln1g;
    const float* nb = (li < 11) ? ln1b + (size_t)(li + 1) * 511 : ln1b;
    k_resproj<<<2048, 256, 0, stream>>>(x, raw1, raw2, raw3, raw4, 4, bpr_l, rw2, li,
                                        ng, nb, actA, (li < 11) ? 1 : 0, ssq);
  }

  k_gemm<64, 64, 1, 0><<<256, 256, 0, stream>>>(
      actA, wfinT, 512, 512, 512, 32, raw1, nullptr, nullptr, nullptr, 512,
      nullptr, nullptr, nullptr, nullptr, nullptr, nullptr, nullptr);
  k_final<<<2048, 256, 0, stream>>>(raw1, bfin, lnfg, lnfb, (float*)d_out);
}